// Round 11
// baseline (154.957 us; speedup 1.0000x reference)
//
#include <hip/hip_runtime.h>
#include <math.h>

#define C_DIM 1024
#define B_SZ 2
#define N_SEQ 2048
#define M_ROWS (B_SZ * N_SEQ)   // 4096
#define KDIM 1024
#define G1_SLOT 10240           // ushorts per 20KB gemm1 slot
#define G2_SLOT 6144            // ushorts per 12KB gemm2 slot

typedef float  f32x4   __attribute__((ext_vector_type(4)));
typedef short  bf16x8  __attribute__((ext_vector_type(8)));
typedef short  short4v __attribute__((ext_vector_type(4)));
typedef short  short8v __attribute__((ext_vector_type(8)));

__device__ __forceinline__ float elu1(float v) {
    return v > 0.f ? v + 1.f : expf(v);
}

__device__ __forceinline__ ushort f2bf(float f) {
    union { float f; unsigned u; } x; x.f = f;
    unsigned r = (x.u + 0x7fffu + ((x.u >> 16) & 1u)) >> 16;  // RNE
    return (ushort)r;
}
__device__ __forceinline__ float bf2f(ushort b) {
    union { unsigned u; float f; } x; x.u = ((unsigned)b) << 16;
    return x.f;
}

#define VMCNT(n) asm volatile("s_waitcnt vmcnt(" #n ")" ::: "memory")
#define BAR      __builtin_amdgcn_s_barrier()

__device__ __forceinline__ void gl16(const ushort* g, ushort* l) {
    __builtin_amdgcn_global_load_lds(
        (const __attribute__((address_space(1))) unsigned int*)g,
        (__attribute__((address_space(3))) unsigned int*)l,
        16, 0, 0);
}

// ---------------------------------------------------------------------------
// fp32 -> bf16 hi/lo split for all 4 inputs in one launch. 8 elems/thread.
// ---------------------------------------------------------------------------
__global__ __launch_bounds__(256)
void split_all_kernel(const float* __restrict__ x, const float* __restrict__ Wq,
                      const float* __restrict__ Wkv, const float* __restrict__ Wo,
                      ushort* __restrict__ xhi, ushort* __restrict__ xlo,
                      ushort* __restrict__ Whi, ushort* __restrict__ Wlo,
                      ushort* __restrict__ Wohi, ushort* __restrict__ Wolo)
{
    const int i = blockIdx.x * 256 + threadIdx.x;   // 0..1048575
    const float* src; ushort* dh; ushort* dl; int off;
    if (i < 524288)        { src = x;   dh = xhi;  dl = xlo;  off = i; }
    else if (i < 655360)   { src = Wq;  dh = Whi;  dl = Wlo;  off = i - 524288; }
    else if (i < 917504)   { src = Wkv; dh = Whi + (1u << 20); dl = Wlo + (1u << 20); off = i - 655360; }
    else                   { src = Wo;  dh = Wohi; dl = Wolo; off = i - 917504; }

    const float4 a = ((const float4*)src)[off * 2];
    const float4 b = ((const float4*)src)[off * 2 + 1];
    const float v[8] = {a.x, a.y, a.z, a.w, b.x, b.y, b.z, b.w};
    ushort hv[8], lv[8];
    #pragma unroll
    for (int j = 0; j < 8; ++j) {
        hv[j] = f2bf(v[j]);
        lv[j] = f2bf(v[j] - bf2f(hv[j]));
    }
    short8v H = {(short)hv[0],(short)hv[1],(short)hv[2],(short)hv[3],
                 (short)hv[4],(short)hv[5],(short)hv[6],(short)hv[7]};
    short8v L = {(short)lv[0],(short)lv[1],(short)lv[2],(short)lv[3],
                 (short)lv[4],(short)lv[5],(short)lv[6],(short)lv[7]};
    *(short8v*)&dh[(size_t)off * 8] = H;
    *(short8v*)&dl[(size_t)off * 8] = L;
}

// ---------------------------------------------------------------------------
// GEMM1: QKV = [x][Wq;Wkv]^T, 3-term split-bf16, 128x192 tile, BK=32,
// 256 threads = 4 waves (2M x 2N), wave tile 64x96. Grid 512 = 32m x 16n
// -> 2 BLOCKS/CU (80KB LDS each): independent wave streams per SIMD hide
// barrier-convergence stalls. 3-phase / 2-barrier per kt, depth-3 pipeline
// (5-load units, counted vmcnt(10); edges 5/0).
// ---------------------------------------------------------------------------
__global__ __launch_bounds__(256, 2)
void gemm1_mfma256_kernel(const ushort* __restrict__ Ahi, const ushort* __restrict__ Alo,
                          const ushort* __restrict__ Bhi, const ushort* __restrict__ Blo,
                          float* __restrict__ dst)
{
    extern __shared__ ushort smem[];   // 4 slots x 10240 ushorts (80 KB)

    const int bid = blockIdx.x;
    const int wg  = (bid & 7) * 64 + (bid >> 3);    // bijective: 512 = 8*64
    const int m0  = (wg >> 4) * 128;                // 32 m-tiles
    const int n0  = (wg & 15) * 192;                // 16 n-tiles

    const int t    = threadIdx.x;
    const int lane = t & 63;
    const int w    = t >> 6;       // 0..3
    const int wr   = w >> 1;       // 0..1  (M half, 64 rows)
    const int wc   = w & 1;        // 0..1  (N half, 96 cols)

    // staging: thread t -> row t>>2 within each 64-row issue, LDS chunk t&3
    const int gch     = (t & 3) ^ ((t >> 3) & 3);
    const size_t rowA  = (size_t)(m0 + (t >> 2)) * KDIM + gch * 8;   // A rows 0..63
    const size_t rowA2 = rowA + (size_t)64 * KDIM;                   // A rows 64..127
    const size_t rowB  = (size_t)(n0 + (t >> 2)) * KDIM + gch * 8;   // B rows 0..63
    const size_t rowB2 = rowB + (size_t)64 * KDIM;                   // 64..127
    const size_t rowB3 = rowB + (size_t)128 * KDIM;                  // 128..191
    const int wl      = w * 512;   // ushorts per wave within an issue

    // fragment addressing (16x16x32: row = lane&15, k-chunk = lane>>4)
    const int frow = lane & 15;
    const int cc   = (lane >> 4) ^ ((lane >> 1) & 3);
    const int aoff = (wr * 64 + frow) * 32 + cc * 8;
    const int boff = 4096 + (wc * 96 + frow) * 32 + cc * 8;

    f32x4 acc[4][6];
    #pragma unroll
    for (int mi = 0; mi < 4; ++mi)
        #pragma unroll
        for (int nj = 0; nj < 6; ++nj)
            acc[mi][nj] = (f32x4){0.f, 0.f, 0.f, 0.f};

    #define STAGE_A(src, slotp, koff)                                        \
        do {                                                                 \
            ushort* sl_ = (slotp);                                           \
            gl16((src) + rowA  + (koff), sl_ + wl);                          \
            gl16((src) + rowA2 + (koff), sl_ + 2048 + wl);                   \
        } while (0)
    #define STAGE_B(src, slotp, koff)                                        \
        do {                                                                 \
            ushort* sl_ = (slotp);                                           \
            gl16((src) + rowB  + (koff), sl_ + 4096 + wl);                   \
            gl16((src) + rowB2 + (koff), sl_ + 6144 + wl);                   \
            gl16((src) + rowB3 + (koff), sl_ + 8192 + wl);                   \
        } while (0)

    // prologue: hi(0)->slot0, lo(0)->slot1, hi(1)->slot2  (15 loads in flight)
    STAGE_A(Ahi, smem, 0);
    STAGE_B(Bhi, smem, 0);
    STAGE_A(Alo, smem + G1_SLOT, 0);
    STAGE_B(Blo, smem + G1_SLOT, 0);
    STAGE_A(Ahi, smem + 2 * G1_SLOT, 32);
    STAGE_B(Bhi, smem + 2 * G1_SLOT, 32);

    #pragma unroll 1
    for (int kt = 0; kt < 32; ++kt) {
        ushort* sh = smem + ((2 * kt) & 3) * G1_SLOT;      // hi(kt)
        ushort* sl = smem + ((2 * kt + 1) & 3) * G1_SLOT;  // lo(kt)
        ushort* nl = smem + ((2 * kt + 3) & 3) * G1_SLOT;  // lo(kt+1) dest
        const int kn1 = (kt + 1) * 32;
        const int kn2 = (kt + 2) * 32;

        bf16x8 ah[4], bh[6], bl[6], al[4];

        // ---- ph1: hi(kt) valid; stage lo(kt+1)
        if (kt < 31) { VMCNT(10); } else { VMCNT(5); }
        BAR;
        if (kt < 31) { STAGE_A(Alo, nl, kn1); STAGE_B(Blo, nl, kn1); }
        #pragma unroll
        for (int mi = 0; mi < 4; ++mi)
            ah[mi] = *(const bf16x8*)(sh + aoff + mi * 512);
        #pragma unroll
        for (int nj = 0; nj < 6; ++nj)
            bh[nj] = *(const bf16x8*)(sh + boff + nj * 512);
        __builtin_amdgcn_s_setprio(1);
        #pragma unroll
        for (int mi = 0; mi < 4; ++mi)
            #pragma unroll
            for (int nj = 0; nj < 6; ++nj)
                acc[mi][nj] = __builtin_amdgcn_mfma_f32_16x16x32_bf16(
                    ah[mi], bh[nj], acc[mi][nj], 0, 0, 0);
        __builtin_amdgcn_s_setprio(0);

        // ---- ph2: lo(kt) valid; stage hi(kt+2) into sh (safe: ph1 reads done)
        if (kt < 31) { VMCNT(10); } else { VMCNT(0); }
        BAR;
        if (kt < 30) { STAGE_A(Ahi, sh, kn2); STAGE_B(Bhi, sh, kn2); }
        #pragma unroll
        for (int nj = 0; nj < 6; ++nj)
            bl[nj] = *(const bf16x8*)(sl + boff + nj * 512);
        #pragma unroll
        for (int mi = 0; mi < 4; ++mi)
            al[mi] = *(const bf16x8*)(sl + aoff + mi * 512);
        __builtin_amdgcn_s_setprio(1);
        #pragma unroll
        for (int mi = 0; mi < 4; ++mi)
            #pragma unroll
            for (int nj = 0; nj < 6; ++nj)
                acc[mi][nj] = __builtin_amdgcn_mfma_f32_16x16x32_bf16(
                    ah[mi], bl[nj], acc[mi][nj], 0, 0, 0);
        __builtin_amdgcn_s_setprio(0);

        // ---- ph3: register-only
        __builtin_amdgcn_s_setprio(1);
        #pragma unroll
        for (int mi = 0; mi < 4; ++mi)
            #pragma unroll
            for (int nj = 0; nj < 6; ++nj)
                acc[mi][nj] = __builtin_amdgcn_mfma_f32_16x16x32_bf16(
                    al[mi], bh[nj], acc[mi][nj], 0, 0, 0);
        __builtin_amdgcn_s_setprio(0);
    }
    #undef STAGE_A
    #undef STAGE_B

    const int erow  = m0 + wr * 64 + (lane >> 4) * 4;
    const int ecol0 = n0 + wc * 96 + frow;
    #pragma unroll
    for (int mi = 0; mi < 4; ++mi) {
        #pragma unroll
        for (int j = 0; j < 4; ++j) {
            const int row = erow + mi * 16 + j;
            #pragma unroll
            for (int nj = 0; nj < 6; ++nj) {
                const int col = ecol0 + nj * 16;
                float v = acc[mi][nj][j];
                if (col < 2048) v = elu1(v);
                dst[(size_t)row * 3072 + col] = v;
            }
        }
    }
}

// ---------------------------------------------------------------------------
// GEMM2: out = O1 @ Wo^T + bo. 64x128 tile, BK=32, 4 waves (1M x 4N),
// wave tile 64x32. Grid 512 = 64m x 8n -> 2 blocks/CU (48KB LDS).
// 3-phase depth-3 pipeline (3-load units -> vmcnt(6), edges 3/0).
// ---------------------------------------------------------------------------
__global__ __launch_bounds__(256, 3)
void gemm2_mfma_kernel(const ushort* __restrict__ Ahi, const ushort* __restrict__ Alo,
                       const ushort* __restrict__ Bhi, const ushort* __restrict__ Blo,
                       const float* __restrict__ bias, float* __restrict__ dst)
{
    __shared__ ushort smem[4 * G2_SLOT];   // 48 KB

    const int bid = blockIdx.x;
    const int wg  = (bid & 7) * 64 + (bid >> 3);    // bijective: 512 = 8*64
    const int m0  = (wg >> 3) * 64;                 // 64 m-tiles
    const int n0  = (wg & 7) * 128;                 // 8 n-tiles

    const int t    = threadIdx.x;
    const int lane = t & 63;
    const int w    = t >> 6;      // 0..3 (N quarters, 32 cols each)

    const int gch     = (t & 3) ^ ((t >> 3) & 3);
    const size_t rowA  = (size_t)(m0 + (t >> 2)) * KDIM + gch * 8;   // 64 rows
    const size_t rowB  = (size_t)(n0 + (t >> 2)) * KDIM + gch * 8;   // rows 0..63
    const size_t rowB2 = rowB + (size_t)64 * KDIM;                   // 64..127
    const int wl      = w * 512;

    const int frow = lane & 15;
    const int cc   = (lane >> 4) ^ ((lane >> 1) & 3);
    const int aoff = frow * 32 + cc * 8;
    const int boff = 2048 + (w * 32 + frow) * 32 + cc * 8;

    f32x4 acc[4][2];
    #pragma unroll
    for (int mi = 0; mi < 4; ++mi)
        #pragma unroll
        for (int nj = 0; nj < 2; ++nj)
            acc[mi][nj] = (f32x4){0.f, 0.f, 0.f, 0.f};

    #define STAGE2(srcA, srcB, slotp, koff)                                  \
        do {                                                                 \
            ushort* p_ = (slotp);                                            \
            gl16((srcA) + rowA  + (koff), p_ + wl);                          \
            gl16((srcB) + rowB  + (koff), p_ + 2048 + wl);                   \
            gl16((srcB) + rowB2 + (koff), p_ + 4096 + wl);                   \
        } while (0)

    // prologue: hi(0)->slot0, lo(0)->slot1, hi(1)->slot2  (9 loads in flight)
    STAGE2(Ahi, Bhi, smem, 0);
    STAGE2(Alo, Blo, smem + G2_SLOT, 0);
    STAGE2(Ahi, Bhi, smem + 2 * G2_SLOT, 32);

    #pragma unroll 1
    for (int kt = 0; kt < 32; ++kt) {
        ushort* sh = smem + ((2 * kt) & 3) * G2_SLOT;
        ushort* sl = smem + ((2 * kt + 1) & 3) * G2_SLOT;
        ushort* nl = smem + ((2 * kt + 3) & 3) * G2_SLOT;
        const int kn1 = (kt + 1) * 32;
        const int kn2 = (kt + 2) * 32;

        bf16x8 ah[4], bh[2], bl[2], al[4];

        // ---- ph1: hh
        if (kt < 31) { VMCNT(6); } else { VMCNT(3); }
        BAR;
        if (kt < 31) STAGE2(Alo, Blo, nl, kn1);
        #pragma unroll
        for (int mi = 0; mi < 4; ++mi)
            ah[mi] = *(const bf16x8*)(sh + aoff + mi * 512);
        #pragma unroll
        for (int nj = 0; nj < 2; ++nj)
            bh[nj] = *(const bf16x8*)(sh + boff + nj * 512);
        __builtin_amdgcn_s_setprio(1);
        #pragma unroll
        for (int mi = 0; mi < 4; ++mi)
            #pragma unroll
            for (int nj = 0; nj < 2; ++nj)
                acc[mi][nj] = __builtin_amdgcn_mfma_f32_16x16x32_bf16(
                    ah[mi], bh[nj], acc[mi][nj], 0, 0, 0);
        __builtin_amdgcn_s_setprio(0);

        // ---- ph2: hl
        if (kt < 31) { VMCNT(6); } else { VMCNT(0); }
        BAR;
        if (kt < 30) STAGE2(Ahi, Bhi, sh, kn2);
        #pragma unroll
        for (int nj = 0; nj < 2; ++nj)
            bl[nj] = *(const bf16x8*)(sl + boff + nj * 512);
        #pragma unroll
        for (int mi = 0; mi < 4; ++mi)
            al[mi] = *(const bf16x8*)(sl + aoff + mi * 512);
        __builtin_amdgcn_s_setprio(1);
        #pragma unroll
        for (int mi = 0; mi < 4; ++mi)
            #pragma unroll
            for (int nj = 0; nj < 2; ++nj)
                acc[mi][nj] = __builtin_amdgcn_mfma_f32_16x16x32_bf16(
                    ah[mi], bl[nj], acc[mi][nj], 0, 0, 0);
        __builtin_amdgcn_s_setprio(0);

        // ---- ph3: lh (register-only)
        __builtin_amdgcn_s_setprio(1);
        #pragma unroll
        for (int mi = 0; mi < 4; ++mi)
            #pragma unroll
            for (int nj = 0; nj < 2; ++nj)
                acc[mi][nj] = __builtin_amdgcn_mfma_f32_16x16x32_bf16(
                    al[mi], bh[nj], acc[mi][nj], 0, 0, 0);
        __builtin_amdgcn_s_setprio(0);
    }
    #undef STAGE2

    const int erow  = m0 + (lane >> 4) * 4;
    const int ecol0 = n0 + w * 32 + frow;
    #pragma unroll
    for (int mi = 0; mi < 4; ++mi) {
        #pragma unroll
        for (int j = 0; j < 4; ++j) {
            const int row = erow + mi * 16 + j;
            #pragma unroll
            for (int nj = 0; nj < 2; ++nj) {
                const int col = ecol0 + nj * 16;
                dst[(size_t)row * 1024 + col] = acc[mi][nj][j] + bias[col];
            }
        }
    }
}

// ---------------------------------------------------------------------------
// Partial KV = K_feat^T V and ksum, per (b,h), 8-way N split (256 rows each).
// ---------------------------------------------------------------------------
__global__ __launch_bounds__(256)
void kv_partial_kernel(const float* __restrict__ QKV, float* __restrict__ KVp)
{
    const int bh = blockIdx.x;   // 0..31
    const int s  = blockIdx.y;   // 0..7
    const int b  = bh >> 4;
    const int h  = bh & 15;
    const int t  = threadIdx.x;

    __shared__ float ks[16][64];
    __shared__ float vs[16][64];
    __shared__ float red[4160];

    const int srow = t >> 4;
    const int scol = (t & 15) * 4;
    const size_t gk = (size_t)(b * N_SEQ + s * 256) * 3072 + 1024 + h * 64 + scol;
    const size_t gv = gk + 1024;

    const int rs = t >> 6;
    const int dg = (t >> 3) & 7;
    const int eg = t & 7;
    const int d0 = dg * 8;
    const int e0 = eg * 8;

    float acc[8][8];
    #pragma unroll
    for (int i = 0; i < 8; ++i)
        #pragma unroll
        for (int j = 0; j < 8; ++j) acc[i][j] = 0.f;
    float aks[8] = {0.f, 0.f, 0.f, 0.f, 0.f, 0.f, 0.f, 0.f};

    float4 kr = *(const float4*)&QKV[gk + (size_t)srow * 3072];
    float4 vr = *(const float4*)&QKV[gv + (size_t)srow * 3072];

    for (int it = 0; it < 16; ++it) {
        __syncthreads();
        *(float4*)&ks[srow][scol] = kr;
        *(float4*)&vs[srow][scol] = vr;
        __syncthreads();
        if (it < 15) {
            kr = *(const float4*)&QKV[gk + (size_t)((it + 1) * 16 + srow) * 3072];
            vr = *(const float4*)&QKV[gv + (size_t)((it + 1) * 16 + srow) * 3072];
        }
        #pragma unroll
        for (int rr = 0; rr < 4; ++rr) {
            const int r = rs * 4 + rr;
            const float4 ka = *(const float4*)&ks[r][d0];
            const float4 kb = *(const float4*)&ks[r][d0 + 4];
            const float4 va = *(const float4*)&vs[r][e0];
            const float4 vb = *(const float4*)&vs[r][e0 + 4];
            const float k8[8] = {ka.x, ka.y, ka.z, ka.w, kb.x, kb.y, kb.z, kb.w};
            const float v8[8] = {va.x, va.y, va.z, va.w, vb.x, vb.y, vb.z, vb.w};
            #pragma unroll
            for (int i = 0; i < 8; ++i)
                #pragma unroll
                for (int j = 0; j < 8; ++j)
                    acc[i][j] += k8[i] * v8[j];
            if (eg == 0) {
                #pragma unroll
                for (int i = 0; i < 8; ++i) aks[i] += k8[i];
            }
        }
    }

    #pragma unroll 1
    for (int step = 1; step < 4; ++step) {
        __syncthreads();
        if (rs == step) {
            #pragma unroll
            for (int i = 0; i < 8; ++i)
                #pragma unroll
                for (int j = 0; j < 8; ++j)
                    red[(d0 + i) * 64 + e0 + j] = acc[i][j];
            if (eg == 0) {
                #pragma unroll
                for (int i = 0; i < 8; ++i) red[4096 + d0 + i] = aks[i];
            }
        }
        __syncthreads();
        if (rs == 0) {
            #pragma unroll
            for (int i = 0; i < 8; ++i)
                #pragma unroll
                for (int j = 0; j < 8; ++j)
                    acc[i][j] += red[(d0 + i) * 64 + e0 + j];
            if (eg == 0) {
                #pragma unroll
                for (int i = 0; i < 8; ++i) aks[i] += red[4096 + d0 + i];
            }
        }
    }

    if (rs == 0) {
        float* outp = KVp + ((size_t)s * 32 + bh) * 4160;
        #pragma unroll
        for (int i = 0; i < 8; ++i) {
            float4 o0 = {acc[i][0], acc[i][1], acc[i][2], acc[i][3]};
            float4 o1 = {acc[i][4], acc[i][5], acc[i][6], acc[i][7]};
            *(float4*)(outp + (d0 + i) * 64 + e0)     = o0;
            *(float4*)(outp + (d0 + i) * 64 + e0 + 4) = o1;
        }
        if (eg == 0) {
            #pragma unroll
            for (int i = 0; i < 8; ++i) outp[4096 + d0 + i] = aks[i];
        }
    }
}

__global__ __launch_bounds__(256)
void kv_reduce_kernel(const float* __restrict__ KVp, float* __restrict__ KVf)
{
    const int idx = blockIdx.x * 256 + threadIdx.x;
    if (idx < 32 * 4160) {
        float s = 0.f;
        #pragma unroll
        for (int i = 0; i < 8; ++i) s += KVp[(size_t)i * (32 * 4160) + idx];
        KVf[idx] = s;
    }
}

// ---------------------------------------------------------------------------
// O1[n, h*64+e] = Z * sum_d q[n,d]*KV[d,e], Z = 1/(q.ksum + 1e-6); bf16 hi/lo out
// ---------------------------------------------------------------------------
__global__ __launch_bounds__(256)
void attn_apply_kernel(const float* __restrict__ QKV, const float* __restrict__ KVf,
                       ushort* __restrict__ O1hi, ushort* __restrict__ O1lo)
{
    const int bh = blockIdx.x;
    const int b = bh >> 4, h = bh & 15;
    const int n0 = blockIdx.y * 16;
    const int t = threadIdx.x;
    const int r  = t >> 4;
    const int e0 = (t & 15) * 4;

    __shared__ float kvs[64][68];
    __shared__ float qs[16][68];
    __shared__ float ksums[64];

    const float* kvb = KVf + (size_t)bh * 4160;
    for (int i = t; i < 4096; i += 256)
        kvs[i >> 6][i & 63] = kvb[i];
    if (t < 64) ksums[t] = kvb[4096 + t];
    {
        const int rr = t >> 4, cc2 = (t & 15) * 4;
        *(float4*)&qs[rr][cc2] =
            *(const float4*)&QKV[(size_t)(b * N_SEQ + n0 + rr) * 3072 + h * 64 + cc2];
    }
    __syncthreads();

    float4 acc = {0.f, 0.f, 0.f, 0.f};
    float accz = 0.f;
    #pragma unroll
    for (int d = 0; d < 64; ++d) {
        const float qv = qs[r][d];
        const float4 kvv = *(const float4*)&kvs[d][e0];
        acc.x += qv * kvv.x; acc.y += qv * kvv.y;
        acc.z += qv * kvv.z; acc.w += qv * kvv.w;
        accz += qv * ksums[d];
    }
    const float Z = 1.f / (accz + 1e-6f);
    const float vv[4] = {acc.x * Z, acc.y * Z, acc.z * Z, acc.w * Z};
    ushort hv[4], lv[4];
    #pragma unroll
    for (int j = 0; j < 4; ++j) {
        hv[j] = f2bf(vv[j]);
        lv[j] = f2bf(vv[j] - bf2f(hv[j]));
    }
    const size_t off = (size_t)(b * N_SEQ + n0 + r) * C_DIM + h * 64 + e0;
    short4v H = {(short)hv[0], (short)hv[1], (short)hv[2], (short)hv[3]};
    short4v L = {(short)lv[0], (short)lv[1], (short)lv[2], (short)lv[3]};
    *(short4v*)&O1hi[off] = H;
    *(short4v*)&O1lo[off] = L;
}

extern "C" void kernel_launch(void* const* d_in, const int* in_sizes, int n_in,
                              void* d_out, int out_size, void* d_ws, size_t ws_size,
                              hipStream_t stream)
{
    const float* x   = (const float*)d_in[0];
    const float* Wq  = (const float*)d_in[1];
    const float* Wkv = (const float*)d_in[2];
    const float* Wo  = (const float*)d_in[3];
    const float* bo  = (const float*)d_in[4];
    float* out = (float*)d_out;

    float* ws   = (float*)d_ws;
    float* QKV  = ws;                                  // 4096*3072 f32
    float* KVp  = QKV + (size_t)M_ROWS * 3072;         // 8*32*4160
    float* KVf  = KVp + (size_t)8 * 32 * 4160;         // 32*4160
    ushort* xhi = (ushort*)(KVf + 32 * 4160);          // 4096*1024 bf16 each
    ushort* xlo = xhi + (size_t)M_ROWS * 1024;
    ushort* Whi = xlo + (size_t)M_ROWS * 1024;         // 3072*1024 (Wq;Wkv)
    ushort* Wlo = Whi + (size_t)3072 * 1024;
    ushort* Wohi = Wlo + (size_t)3072 * 1024;          // 1024*1024
    ushort* Wolo = Wohi + (size_t)1024 * 1024;
    ushort* O1hi = xhi;                                // alias: x dead after GEMM1
    ushort* O1lo = xlo;

    hipFuncSetAttribute((const void*)gemm1_mfma256_kernel,
                        hipFuncAttributeMaxDynamicSharedMemorySize, 81920);

    // 0. split fp32 -> bf16 hi/lo
    split_all_kernel<<<dim3(4096), 256, 0, stream>>>(
        x, Wq, Wkv, Wo, xhi, xlo, Whi, Wlo, Wohi, Wolo);

    // 1. fused q/k/v projections + elu+1 on q,k (2 blocks/CU)
    gemm1_mfma256_kernel<<<dim3(512), 256, 81920, stream>>>(xhi, xlo, Whi, Wlo, QKV);

    // 2-3. KV = K^T V + ksum (8-way split + deterministic reduce)
    kv_partial_kernel<<<dim3(32, 8), 256, 0, stream>>>(QKV, KVp);
    kv_reduce_kernel<<<dim3((32 * 4160 + 255) / 256), 256, 0, stream>>>(KVp, KVf);

    // 4. O1 = Z * (q @ KV), bf16 hi/lo out
    attn_apply_kernel<<<dim3(32, 128), 256, 0, stream>>>(QKV, KVf, O1hi, O1lo);

    // 5. final projection + bias (2 blocks/CU)
    gemm2_mfma_kernel<<<dim3(512), 256, 0, stream>>>(O1hi, O1lo, Wohi, Wolo, bo, out);
}

// Round 12
// 151.431 us; speedup vs baseline: 1.0233x; 1.0233x over previous
//
#include <hip/hip_runtime.h>
#include <math.h>

#define C_DIM 1024
#define B_SZ 2
#define N_SEQ 2048
#define M_ROWS (B_SZ * N_SEQ)   // 4096
#define KDIM 1024
#define G1_SLOT 10240           // ushorts per 20KB gemm1 slot
#define G2_SLOT 8192            // ushorts per 16KB gemm2 slot

typedef float  f32x4   __attribute__((ext_vector_type(4)));
typedef short  bf16x8  __attribute__((ext_vector_type(8)));
typedef short  short4v __attribute__((ext_vector_type(4)));
typedef short  short8v __attribute__((ext_vector_type(8)));

__device__ __forceinline__ float elu1(float v) {
    return v > 0.f ? v + 1.f : expf(v);
}

__device__ __forceinline__ ushort f2bf(float f) {
    union { float f; unsigned u; } x; x.f = f;
    unsigned r = (x.u + 0x7fffu + ((x.u >> 16) & 1u)) >> 16;  // RNE
    return (ushort)r;
}
__device__ __forceinline__ float bf2f(ushort b) {
    union { unsigned u; float f; } x; x.u = ((unsigned)b) << 16;
    return x.f;
}

#define VMCNT(n) asm volatile("s_waitcnt vmcnt(" #n ")" ::: "memory")
#define BAR      __builtin_amdgcn_s_barrier()

__device__ __forceinline__ void gl16(const ushort* g, ushort* l) {
    __builtin_amdgcn_global_load_lds(
        (const __attribute__((address_space(1))) unsigned int*)g,
        (__attribute__((address_space(3))) unsigned int*)l,
        16, 0, 0);
}

// ---------------------------------------------------------------------------
// fp32 -> bf16 hi/lo split for all 4 inputs in one launch. 8 elems/thread.
// ---------------------------------------------------------------------------
__global__ __launch_bounds__(256)
void split_all_kernel(const float* __restrict__ x, const float* __restrict__ Wq,
                      const float* __restrict__ Wkv, const float* __restrict__ Wo,
                      ushort* __restrict__ xhi, ushort* __restrict__ xlo,
                      ushort* __restrict__ Whi, ushort* __restrict__ Wlo,
                      ushort* __restrict__ Wohi, ushort* __restrict__ Wolo)
{
    const int i = blockIdx.x * 256 + threadIdx.x;   // 0..1048575
    const float* src; ushort* dh; ushort* dl; int off;
    if (i < 524288)        { src = x;   dh = xhi;  dl = xlo;  off = i; }
    else if (i < 655360)   { src = Wq;  dh = Whi;  dl = Wlo;  off = i - 524288; }
    else if (i < 917504)   { src = Wkv; dh = Whi + (1u << 20); dl = Wlo + (1u << 20); off = i - 655360; }
    else                   { src = Wo;  dh = Wohi; dl = Wolo; off = i - 917504; }

    const float4 a = ((const float4*)src)[off * 2];
    const float4 b = ((const float4*)src)[off * 2 + 1];
    const float v[8] = {a.x, a.y, a.z, a.w, b.x, b.y, b.z, b.w};
    ushort hv[8], lv[8];
    #pragma unroll
    for (int j = 0; j < 8; ++j) {
        hv[j] = f2bf(v[j]);
        lv[j] = f2bf(v[j] - bf2f(hv[j]));
    }
    short8v H = {(short)hv[0],(short)hv[1],(short)hv[2],(short)hv[3],
                 (short)hv[4],(short)hv[5],(short)hv[6],(short)hv[7]};
    short8v L = {(short)lv[0],(short)lv[1],(short)lv[2],(short)lv[3],
                 (short)lv[4],(short)lv[5],(short)lv[6],(short)lv[7]};
    *(short8v*)&dh[(size_t)off * 8] = H;
    *(short8v*)&dl[(size_t)off * 8] = L;
}

// ---------------------------------------------------------------------------
// GEMM1: QKV = [x][Wq;Wkv]^T, 3-term split-bf16, 128x192 tile, BK=32,
// 256 threads = 4 waves (2M x 2N), wave tile 64x96. Grid 512 = 32m x 16n
// -> 2 BLOCKS/CU (80KB LDS each). 3-phase / 2-barrier per kt, depth-3
// pipeline (5-load units, counted vmcnt(10); edges 5/0).  [best measured]
// ---------------------------------------------------------------------------
__global__ __launch_bounds__(256, 2)
void gemm1_mfma256_kernel(const ushort* __restrict__ Ahi, const ushort* __restrict__ Alo,
                          const ushort* __restrict__ Bhi, const ushort* __restrict__ Blo,
                          float* __restrict__ dst)
{
    extern __shared__ ushort smem[];   // 4 slots x 10240 ushorts (80 KB)

    const int bid = blockIdx.x;
    const int wg  = (bid & 7) * 64 + (bid >> 3);    // bijective: 512 = 8*64
    const int m0  = (wg >> 4) * 128;                // 32 m-tiles
    const int n0  = (wg & 15) * 192;                // 16 n-tiles

    const int t    = threadIdx.x;
    const int lane = t & 63;
    const int w    = t >> 6;       // 0..3
    const int wr   = w >> 1;       // 0..1  (M half, 64 rows)
    const int wc   = w & 1;        // 0..1  (N half, 96 cols)

    const int gch     = (t & 3) ^ ((t >> 3) & 3);
    const size_t rowA  = (size_t)(m0 + (t >> 2)) * KDIM + gch * 8;   // A rows 0..63
    const size_t rowA2 = rowA + (size_t)64 * KDIM;                   // A rows 64..127
    const size_t rowB  = (size_t)(n0 + (t >> 2)) * KDIM + gch * 8;   // B rows 0..63
    const size_t rowB2 = rowB + (size_t)64 * KDIM;                   // 64..127
    const size_t rowB3 = rowB + (size_t)128 * KDIM;                  // 128..191
    const int wl      = w * 512;

    const int frow = lane & 15;
    const int cc   = (lane >> 4) ^ ((lane >> 1) & 3);
    const int aoff = (wr * 64 + frow) * 32 + cc * 8;
    const int boff = 4096 + (wc * 96 + frow) * 32 + cc * 8;

    f32x4 acc[4][6];
    #pragma unroll
    for (int mi = 0; mi < 4; ++mi)
        #pragma unroll
        for (int nj = 0; nj < 6; ++nj)
            acc[mi][nj] = (f32x4){0.f, 0.f, 0.f, 0.f};

    #define STAGE_A(src, slotp, koff)                                        \
        do {                                                                 \
            ushort* sl_ = (slotp);                                           \
            gl16((src) + rowA  + (koff), sl_ + wl);                          \
            gl16((src) + rowA2 + (koff), sl_ + 2048 + wl);                   \
        } while (0)
    #define STAGE_B(src, slotp, koff)                                        \
        do {                                                                 \
            ushort* sl_ = (slotp);                                           \
            gl16((src) + rowB  + (koff), sl_ + 4096 + wl);                   \
            gl16((src) + rowB2 + (koff), sl_ + 6144 + wl);                   \
            gl16((src) + rowB3 + (koff), sl_ + 8192 + wl);                   \
        } while (0)

    // prologue: hi(0)->slot0, lo(0)->slot1, hi(1)->slot2  (15 loads in flight)
    STAGE_A(Ahi, smem, 0);
    STAGE_B(Bhi, smem, 0);
    STAGE_A(Alo, smem + G1_SLOT, 0);
    STAGE_B(Blo, smem + G1_SLOT, 0);
    STAGE_A(Ahi, smem + 2 * G1_SLOT, 32);
    STAGE_B(Bhi, smem + 2 * G1_SLOT, 32);

    #pragma unroll 1
    for (int kt = 0; kt < 32; ++kt) {
        ushort* sh = smem + ((2 * kt) & 3) * G1_SLOT;      // hi(kt)
        ushort* sl = smem + ((2 * kt + 1) & 3) * G1_SLOT;  // lo(kt)
        ushort* nl = smem + ((2 * kt + 3) & 3) * G1_SLOT;  // lo(kt+1) dest
        const int kn1 = (kt + 1) * 32;
        const int kn2 = (kt + 2) * 32;

        bf16x8 ah[4], bh[6], bl[6], al[4];

        // ---- ph1: hi(kt) valid; stage lo(kt+1)
        if (kt < 31) { VMCNT(10); } else { VMCNT(5); }
        BAR;
        if (kt < 31) { STAGE_A(Alo, nl, kn1); STAGE_B(Blo, nl, kn1); }
        #pragma unroll
        for (int mi = 0; mi < 4; ++mi)
            ah[mi] = *(const bf16x8*)(sh + aoff + mi * 512);
        #pragma unroll
        for (int nj = 0; nj < 6; ++nj)
            bh[nj] = *(const bf16x8*)(sh + boff + nj * 512);
        __builtin_amdgcn_s_setprio(1);
        #pragma unroll
        for (int mi = 0; mi < 4; ++mi)
            #pragma unroll
            for (int nj = 0; nj < 6; ++nj)
                acc[mi][nj] = __builtin_amdgcn_mfma_f32_16x16x32_bf16(
                    ah[mi], bh[nj], acc[mi][nj], 0, 0, 0);
        __builtin_amdgcn_s_setprio(0);

        // ---- ph2: lo(kt) valid; stage hi(kt+2) into sh (safe: ph1 reads done)
        if (kt < 31) { VMCNT(10); } else { VMCNT(0); }
        BAR;
        if (kt < 30) { STAGE_A(Ahi, sh, kn2); STAGE_B(Bhi, sh, kn2); }
        #pragma unroll
        for (int nj = 0; nj < 6; ++nj)
            bl[nj] = *(const bf16x8*)(sl + boff + nj * 512);
        #pragma unroll
        for (int mi = 0; mi < 4; ++mi)
            al[mi] = *(const bf16x8*)(sl + aoff + mi * 512);
        __builtin_amdgcn_s_setprio(1);
        #pragma unroll
        for (int mi = 0; mi < 4; ++mi)
            #pragma unroll
            for (int nj = 0; nj < 6; ++nj)
                acc[mi][nj] = __builtin_amdgcn_mfma_f32_16x16x32_bf16(
                    ah[mi], bl[nj], acc[mi][nj], 0, 0, 0);
        __builtin_amdgcn_s_setprio(0);

        // ---- ph3: register-only
        __builtin_amdgcn_s_setprio(1);
        #pragma unroll
        for (int mi = 0; mi < 4; ++mi)
            #pragma unroll
            for (int nj = 0; nj < 6; ++nj)
                acc[mi][nj] = __builtin_amdgcn_mfma_f32_16x16x32_bf16(
                    al[mi], bh[nj], acc[mi][nj], 0, 0, 0);
        __builtin_amdgcn_s_setprio(0);
    }
    #undef STAGE_A
    #undef STAGE_B

    const int erow  = m0 + wr * 64 + (lane >> 4) * 4;
    const int ecol0 = n0 + wc * 96 + frow;
    #pragma unroll
    for (int mi = 0; mi < 4; ++mi) {
        #pragma unroll
        for (int j = 0; j < 4; ++j) {
            const int row = erow + mi * 16 + j;
            #pragma unroll
            for (int nj = 0; nj < 6; ++nj) {
                const int col = ecol0 + nj * 16;
                float v = acc[mi][nj][j];
                if (col < 2048) v = elu1(v);
                dst[(size_t)row * 3072 + col] = v;
            }
        }
    }
}

// ---------------------------------------------------------------------------
// GEMM2: out = O1 @ Wo^T + bo. 128x128 tile, BK=32, 8 waves (2M x 4N),
// wave tile 64x32. Grid 256 full fill, 2 waves/SIMD. 3-phase depth-3
// pipeline (2-load units -> vmcnt(4), edges 2/0). 64KB LDS.  [R9/R10 config]
// ---------------------------------------------------------------------------
__global__ __launch_bounds__(512, 2)
void gemm2_mfma_kernel(const ushort* __restrict__ Ahi, const ushort* __restrict__ Alo,
                       const ushort* __restrict__ Bhi, const ushort* __restrict__ Blo,
                       const float* __restrict__ bias, float* __restrict__ dst)
{
    __shared__ ushort smem[4 * G2_SLOT];   // 64 KB

    const int bid = blockIdx.x;
    const int wg  = (bid & 7) * 32 + (bid >> 3);    // bijective: 256 = 8*32
    const int m0  = (wg >> 3) * 128;                // 32 m-tiles
    const int n0  = (wg & 7) * 128;                 // 8 n-tiles

    const int t    = threadIdx.x;
    const int lane = t & 63;
    const int w    = t >> 6;      // 0..7
    const int wr   = w >> 2;      // 0..1  (M half, 64 rows)
    const int wc   = w & 3;       // 0..3  (N quarter, 32 cols)

    const int gch     = (t & 3) ^ ((t >> 3) & 3);
    const size_t rowA = (size_t)(m0 + (t >> 2)) * KDIM + gch * 8;
    const size_t rowB = (size_t)(n0 + (t >> 2)) * KDIM + gch * 8;
    const int wl      = w * 512;

    const int frow = lane & 15;
    const int cc   = (lane >> 4) ^ ((lane >> 1) & 3);
    const int aoff = (wr * 64 + frow) * 32 + cc * 8;
    const int boff = 4096 + (wc * 32 + frow) * 32 + cc * 8;

    f32x4 acc[4][2];
    #pragma unroll
    for (int mi = 0; mi < 4; ++mi)
        #pragma unroll
        for (int nj = 0; nj < 2; ++nj)
            acc[mi][nj] = (f32x4){0.f, 0.f, 0.f, 0.f};

    #define STAGE2(srcA, srcB, slotp, koff)                                  \
        do {                                                                 \
            ushort* p_ = (slotp);                                            \
            gl16((srcA) + rowA + (koff), p_ + wl);                           \
            gl16((srcB) + rowB + (koff), p_ + 4096 + wl);                    \
        } while (0)

    // prologue: hi(0)->slot0, lo(0)->slot1, hi(1)->slot2  (6 loads in flight)
    STAGE2(Ahi, Bhi, smem, 0);
    STAGE2(Alo, Blo, smem + G2_SLOT, 0);
    STAGE2(Ahi, Bhi, smem + 2 * G2_SLOT, 32);

    #pragma unroll 1
    for (int kt = 0; kt < 32; ++kt) {
        ushort* sh = smem + ((2 * kt) & 3) * G2_SLOT;
        ushort* sl = smem + ((2 * kt + 1) & 3) * G2_SLOT;
        ushort* nl = smem + ((2 * kt + 3) & 3) * G2_SLOT;
        const int kn1 = (kt + 1) * 32;
        const int kn2 = (kt + 2) * 32;

        bf16x8 ah[4], bh[2], bl[2], al[4];

        // ---- ph1: hh
        if (kt < 31) { VMCNT(4); } else { VMCNT(2); }
        BAR;
        if (kt < 31) STAGE2(Alo, Blo, nl, kn1);
        #pragma unroll
        for (int mi = 0; mi < 4; ++mi)
            ah[mi] = *(const bf16x8*)(sh + aoff + mi * 512);
        #pragma unroll
        for (int nj = 0; nj < 2; ++nj)
            bh[nj] = *(const bf16x8*)(sh + boff + nj * 512);
        __builtin_amdgcn_s_setprio(1);
        #pragma unroll
        for (int mi = 0; mi < 4; ++mi)
            #pragma unroll
            for (int nj = 0; nj < 2; ++nj)
                acc[mi][nj] = __builtin_amdgcn_mfma_f32_16x16x32_bf16(
                    ah[mi], bh[nj], acc[mi][nj], 0, 0, 0);
        __builtin_amdgcn_s_setprio(0);

        // ---- ph2: hl
        if (kt < 31) { VMCNT(4); } else { VMCNT(0); }
        BAR;
        if (kt < 30) STAGE2(Ahi, Bhi, sh, kn2);
        #pragma unroll
        for (int nj = 0; nj < 2; ++nj)
            bl[nj] = *(const bf16x8*)(sl + boff + nj * 512);
        #pragma unroll
        for (int mi = 0; mi < 4; ++mi)
            al[mi] = *(const bf16x8*)(sl + aoff + mi * 512);
        __builtin_amdgcn_s_setprio(1);
        #pragma unroll
        for (int mi = 0; mi < 4; ++mi)
            #pragma unroll
            for (int nj = 0; nj < 2; ++nj)
                acc[mi][nj] = __builtin_amdgcn_mfma_f32_16x16x32_bf16(
                    ah[mi], bl[nj], acc[mi][nj], 0, 0, 0);
        __builtin_amdgcn_s_setprio(0);

        // ---- ph3: lh (register-only)
        __builtin_amdgcn_s_setprio(1);
        #pragma unroll
        for (int mi = 0; mi < 4; ++mi)
            #pragma unroll
            for (int nj = 0; nj < 2; ++nj)
                acc[mi][nj] = __builtin_amdgcn_mfma_f32_16x16x32_bf16(
                    al[mi], bh[nj], acc[mi][nj], 0, 0, 0);
        __builtin_amdgcn_s_setprio(0);
    }
    #undef STAGE2

    const int erow  = m0 + wr * 64 + (lane >> 4) * 4;
    const int ecol0 = n0 + wc * 32 + frow;
    #pragma unroll
    for (int mi = 0; mi < 4; ++mi) {
        #pragma unroll
        for (int j = 0; j < 4; ++j) {
            const int row = erow + mi * 16 + j;
            #pragma unroll
            for (int nj = 0; nj < 2; ++nj) {
                const int col = ecol0 + nj * 16;
                dst[(size_t)row * 1024 + col] = acc[mi][nj][j] + bias[col];
            }
        }
    }
}

// ---------------------------------------------------------------------------
// Partial KV = K_feat^T V and ksum, per (b,h), 8-way N split (256 rows each).
// ---------------------------------------------------------------------------
__global__ __launch_bounds__(256)
void kv_partial_kernel(const float* __restrict__ QKV, float* __restrict__ KVp)
{
    const int bh = blockIdx.x;   // 0..31
    const int s  = blockIdx.y;   // 0..7
    const int b  = bh >> 4;
    const int h  = bh & 15;
    const int t  = threadIdx.x;

    __shared__ float ks[16][64];
    __shared__ float vs[16][64];
    __shared__ float red[4160];

    const int srow = t >> 4;
    const int scol = (t & 15) * 4;
    const size_t gk = (size_t)(b * N_SEQ + s * 256) * 3072 + 1024 + h * 64 + scol;
    const size_t gv = gk + 1024;

    const int rs = t >> 6;
    const int dg = (t >> 3) & 7;
    const int eg = t & 7;
    const int d0 = dg * 8;
    const int e0 = eg * 8;

    float acc[8][8];
    #pragma unroll
    for (int i = 0; i < 8; ++i)
        #pragma unroll
        for (int j = 0; j < 8; ++j) acc[i][j] = 0.f;
    float aks[8] = {0.f, 0.f, 0.f, 0.f, 0.f, 0.f, 0.f, 0.f};

    float4 kr = *(const float4*)&QKV[gk + (size_t)srow * 3072];
    float4 vr = *(const float4*)&QKV[gv + (size_t)srow * 3072];

    for (int it = 0; it < 16; ++it) {
        __syncthreads();
        *(float4*)&ks[srow][scol] = kr;
        *(float4*)&vs[srow][scol] = vr;
        __syncthreads();
        if (it < 15) {
            kr = *(const float4*)&QKV[gk + (size_t)((it + 1) * 16 + srow) * 3072];
            vr = *(const float4*)&QKV[gv + (size_t)((it + 1) * 16 + srow) * 3072];
        }
        #pragma unroll
        for (int rr = 0; rr < 4; ++rr) {
            const int r = rs * 4 + rr;
            const float4 ka = *(const float4*)&ks[r][d0];
            const float4 kb = *(const float4*)&ks[r][d0 + 4];
            const float4 va = *(const float4*)&vs[r][e0];
            const float4 vb = *(const float4*)&vs[r][e0 + 4];
            const float k8[8] = {ka.x, ka.y, ka.z, ka.w, kb.x, kb.y, kb.z, kb.w};
            const float v8[8] = {va.x, va.y, va.z, va.w, vb.x, vb.y, vb.z, vb.w};
            #pragma unroll
            for (int i = 0; i < 8; ++i)
                #pragma unroll
                for (int j = 0; j < 8; ++j)
                    acc[i][j] += k8[i] * v8[j];
            if (eg == 0) {
                #pragma unroll
                for (int i = 0; i < 8; ++i) aks[i] += k8[i];
            }
        }
    }

    #pragma unroll 1
    for (int step = 1; step < 4; ++step) {
        __syncthreads();
        if (rs == step) {
            #pragma unroll
            for (int i = 0; i < 8; ++i)
                #pragma unroll
                for (int j = 0; j < 8; ++j)
                    red[(d0 + i) * 64 + e0 + j] = acc[i][j];
            if (eg == 0) {
                #pragma unroll
                for (int i = 0; i < 8; ++i) red[4096 + d0 + i] = aks[i];
            }
        }
        __syncthreads();
        if (rs == 0) {
            #pragma unroll
            for (int i = 0; i < 8; ++i)
                #pragma unroll
                for (int j = 0; j < 8; ++j)
                    acc[i][j] += red[(d0 + i) * 64 + e0 + j];
            if (eg == 0) {
                #pragma unroll
                for (int i = 0; i < 8; ++i) aks[i] += red[4096 + d0 + i];
            }
        }
    }

    if (rs == 0) {
        float* outp = KVp + ((size_t)s * 32 + bh) * 4160;
        #pragma unroll
        for (int i = 0; i < 8; ++i) {
            float4 o0 = {acc[i][0], acc[i][1], acc[i][2], acc[i][3]};
            float4 o1 = {acc[i][4], acc[i][5], acc[i][6], acc[i][7]};
            *(float4*)(outp + (d0 + i) * 64 + e0)     = o0;
            *(float4*)(outp + (d0 + i) * 64 + e0 + 4) = o1;
        }
        if (eg == 0) {
            #pragma unroll
            for (int i = 0; i < 8; ++i) outp[4096 + d0 + i] = aks[i];
        }
    }
}

__global__ __launch_bounds__(256)
void kv_reduce_kernel(const float* __restrict__ KVp, float* __restrict__ KVf)
{
    const int idx = blockIdx.x * 256 + threadIdx.x;
    if (idx < 32 * 4160) {
        float s = 0.f;
        #pragma unroll
        for (int i = 0; i < 8; ++i) s += KVp[(size_t)i * (32 * 4160) + idx];
        KVf[idx] = s;
    }
}

// ---------------------------------------------------------------------------
// O1[n, h*64+e] = Z * sum_d q[n,d]*KV[d,e], Z = 1/(q.ksum + 1e-6); bf16 hi/lo out
// ---------------------------------------------------------------------------
__global__ __launch_bounds__(256)
void attn_apply_kernel(const float* __restrict__ QKV, const float* __restrict__ KVf,
                       ushort* __restrict__ O1hi, ushort* __restrict__ O1lo)
{
    const int bh = blockIdx.x;
    const int b = bh >> 4, h = bh & 15;
    const int n0 = blockIdx.y * 16;
    const int t = threadIdx.x;
    const int r  = t >> 4;
    const int e0 = (t & 15) * 4;

    __shared__ float kvs[64][68];
    __shared__ float qs[16][68];
    __shared__ float ksums[64];

    const float* kvb = KVf + (size_t)bh * 4160;
    for (int i = t; i < 4096; i += 256)
        kvs[i >> 6][i & 63] = kvb[i];
    if (t < 64) ksums[t] = kvb[4096 + t];
    {
        const int rr = t >> 4, cc2 = (t & 15) * 4;
        *(float4*)&qs[rr][cc2] =
            *(const float4*)&QKV[(size_t)(b * N_SEQ + n0 + rr) * 3072 + h * 64 + cc2];
    }
    __syncthreads();

    float4 acc = {0.f, 0.f, 0.f, 0.f};
    float accz = 0.f;
    #pragma unroll
    for (int d = 0; d < 64; ++d) {
        const float qv = qs[r][d];
        const float4 kvv = *(const float4*)&kvs[d][e0];
        acc.x += qv * kvv.x; acc.y += qv * kvv.y;
        acc.z += qv * kvv.z; acc.w += qv * kvv.w;
        accz += qv * ksums[d];
    }
    const float Z = 1.f / (accz + 1e-6f);
    const float vv[4] = {acc.x * Z, acc.y * Z, acc.z * Z, acc.w * Z};
    ushort hv[4], lv[4];
    #pragma unroll
    for (int j = 0; j < 4; ++j) {
        hv[j] = f2bf(vv[j]);
        lv[j] = f2bf(vv[j] - bf2f(hv[j]));
    }
    const size_t off = (size_t)(b * N_SEQ + n0 + r) * C_DIM + h * 64 + e0;
    short4v H = {(short)hv[0], (short)hv[1], (short)hv[2], (short)hv[3]};
    short4v L = {(short)lv[0], (short)lv[1], (short)lv[2], (short)lv[3]};
    *(short4v*)&O1hi[off] = H;
    *(short4v*)&O1lo[off] = L;
}

extern "C" void kernel_launch(void* const* d_in, const int* in_sizes, int n_in,
                              void* d_out, int out_size, void* d_ws, size_t ws_size,
                              hipStream_t stream)
{
    const float* x   = (const float*)d_in[0];
    const float* Wq  = (const float*)d_in[1];
    const float* Wkv = (const float*)d_in[2];
    const float* Wo  = (const float*)d_in[3];
    const float* bo  = (const float*)d_in[4];
    float* out = (float*)d_out;

    float* ws   = (float*)d_ws;
    float* QKV  = ws;                                  // 4096*3072 f32
    float* KVp  = QKV + (size_t)M_ROWS * 3072;         // 8*32*4160
    float* KVf  = KVp + (size_t)8 * 32 * 4160;         // 32*4160
    ushort* xhi = (ushort*)(KVf + 32 * 4160);          // 4096*1024 bf16 each
    ushort* xlo = xhi + (size_t)M_ROWS * 1024;
    ushort* Whi = xlo + (size_t)M_ROWS * 1024;         // 3072*1024 (Wq;Wkv)
    ushort* Wlo = Whi + (size_t)3072 * 1024;
    ushort* Wohi = Wlo + (size_t)3072 * 1024;          // 1024*1024
    ushort* Wolo = Wohi + (size_t)1024 * 1024;
    ushort* O1hi = xhi;                                // alias: x dead after GEMM1
    ushort* O1lo = xlo;

    hipFuncSetAttribute((const void*)gemm1_mfma256_kernel,
                        hipFuncAttributeMaxDynamicSharedMemorySize, 81920);

    // 0. split fp32 -> bf16 hi/lo
    split_all_kernel<<<dim3(4096), 256, 0, stream>>>(
        x, Wq, Wkv, Wo, xhi, xlo, Whi, Wlo, Wohi, Wolo);

    // 1. fused q/k/v projections + elu+1 on q,k (2 blocks/CU)
    gemm1_mfma256_kernel<<<dim3(512), 256, 81920, stream>>>(xhi, xlo, Whi, Wlo, QKV);

    // 2-3. KV = K^T V + ksum (8-way split + deterministic reduce)
    kv_partial_kernel<<<dim3(32, 8), 256, 0, stream>>>(QKV, KVp);
    kv_reduce_kernel<<<dim3((32 * 4160 + 255) / 256), 256, 0, stream>>>(KVp, KVf);

    // 4. O1 = Z * (q @ KV), bf16 hi/lo out
    attn_apply_kernel<<<dim3(32, 128), 256, 0, stream>>>(QKV, KVf, O1hi, O1lo);

    // 5. final projection + bias (R9/R10 config: 8 waves, grid 256)
    gemm2_mfma_kernel<<<dim3(256), 512, 0, stream>>>(O1hi, O1lo, Wohi, Wolo, bo, out);
}

// Round 13
// 139.170 us; speedup vs baseline: 1.1134x; 1.0881x over previous
//
#include <hip/hip_runtime.h>
#include <math.h>

#define C_DIM 1024
#define B_SZ 2
#define N_SEQ 2048
#define M_ROWS (B_SZ * N_SEQ)   // 4096
#define KDIM 1024
#define G1Q_SLOT 6144           // ushorts per 12KB gemm1q slot (A 8KB + B 4KB)
#define G1KV_SLOT 8192          // ushorts per 16KB gemm1kv slot (A 8KB + B 8KB)
#define G2_SLOT 8192            // ushorts per 16KB gemm2 slot

typedef float  f32x4   __attribute__((ext_vector_type(4)));
typedef short  bf16x8  __attribute__((ext_vector_type(8)));
typedef short  short4v __attribute__((ext_vector_type(4)));
typedef short  short8v __attribute__((ext_vector_type(8)));

__device__ __forceinline__ float elu1(float v) {
    return v > 0.f ? v + 1.f : expf(v);
}

__device__ __forceinline__ ushort f2bf(float f) {
    union { float f; unsigned u; } x; x.f = f;
    unsigned r = (x.u + 0x7fffu + ((x.u >> 16) & 1u)) >> 16;  // RNE
    return (ushort)r;
}
__device__ __forceinline__ float bf2f(ushort b) {
    union { unsigned u; float f; } x; x.u = ((unsigned)b) << 16;
    return x.f;
}

#define VMCNT(n) asm volatile("s_waitcnt vmcnt(" #n ")" ::: "memory")
#define BAR      __builtin_amdgcn_s_barrier()

__device__ __forceinline__ void gl16(const ushort* g, ushort* l) {
    __builtin_amdgcn_global_load_lds(
        (const __attribute__((address_space(1))) unsigned int*)g,
        (__attribute__((address_space(3))) unsigned int*)l,
        16, 0, 0);
}

// ---------------------------------------------------------------------------
// fp32 -> bf16 hi/lo split for all 4 inputs in one launch. 8 elems/thread.
// ---------------------------------------------------------------------------
__global__ __launch_bounds__(256)
void split_all_kernel(const float* __restrict__ x, const float* __restrict__ Wq,
                      const float* __restrict__ Wkv, const float* __restrict__ Wo,
                      ushort* __restrict__ xhi, ushort* __restrict__ xlo,
                      ushort* __restrict__ Whi, ushort* __restrict__ Wlo,
                      ushort* __restrict__ Wohi, ushort* __restrict__ Wolo)
{
    const int i = blockIdx.x * 256 + threadIdx.x;   // 0..1048575
    const float* src; ushort* dh; ushort* dl; int off;
    if (i < 524288)        { src = x;   dh = xhi;  dl = xlo;  off = i; }
    else if (i < 655360)   { src = Wq;  dh = Whi;  dl = Wlo;  off = i - 524288; }
    else if (i < 917504)   { src = Wkv; dh = Whi + (1u << 20); dl = Wlo + (1u << 20); off = i - 655360; }
    else                   { src = Wo;  dh = Wohi; dl = Wolo; off = i - 917504; }

    const float4 a = ((const float4*)src)[off * 2];
    const float4 b = ((const float4*)src)[off * 2 + 1];
    const float v[8] = {a.x, a.y, a.z, a.w, b.x, b.y, b.z, b.w};
    ushort hv[8], lv[8];
    #pragma unroll
    for (int j = 0; j < 8; ++j) {
        hv[j] = f2bf(v[j]);
        lv[j] = f2bf(v[j] - bf2f(hv[j]));
    }
    short8v H = {(short)hv[0],(short)hv[1],(short)hv[2],(short)hv[3],
                 (short)hv[4],(short)hv[5],(short)hv[6],(short)hv[7]};
    short8v L = {(short)lv[0],(short)lv[1],(short)lv[2],(short)lv[3],
                 (short)lv[4],(short)lv[5],(short)lv[6],(short)lv[7]};
    *(short8v*)&dh[(size_t)off * 8] = H;
    *(short8v*)&dl[(size_t)off * 8] = L;
}

// ---------------------------------------------------------------------------
// GEMM1Q: Q = elu1(x @ Wq^T), cols [0,1024) of QKV. 3-term split-bf16.
// 128x64 tile, 4 waves (2M x 2N), wave tile 64x32. Grid 512 = 32m x 16n
// -> 2 blocks/CU (48KB LDS). 3-phase / 2-barrier per kt, depth-3 pipeline
// (3-load units, counted vmcnt(6); edges 3/0).
// ---------------------------------------------------------------------------
__global__ __launch_bounds__(256, 2)
void gemm1q_kernel(const ushort* __restrict__ Ahi, const ushort* __restrict__ Alo,
                   const ushort* __restrict__ Bhi, const ushort* __restrict__ Blo,
                   float* __restrict__ dst)
{
    __shared__ ushort smem[4 * G1Q_SLOT];   // 48 KB

    const int bid = blockIdx.x;
    const int wg  = (bid & 7) * 64 + (bid >> 3);    // bijective: 512 = 8*64
    const int m0  = (wg >> 4) * 128;                // 32 m-tiles
    const int n0  = (wg & 15) * 64;                 // 16 n-tiles

    const int t    = threadIdx.x;
    const int lane = t & 63;
    const int w    = t >> 6;       // 0..3
    const int wr   = w >> 1;       // 0..1  (M half, 64 rows)
    const int wc   = w & 1;        // 0..1  (N half, 32 cols)

    const int gch     = (t & 3) ^ ((t >> 3) & 3);
    const size_t rowA  = (size_t)(m0 + (t >> 2)) * KDIM + gch * 8;   // A rows 0..63
    const size_t rowA2 = rowA + (size_t)64 * KDIM;                   // A rows 64..127
    const size_t rowB  = (size_t)(n0 + (t >> 2)) * KDIM + gch * 8;   // B rows 0..63
    const int wl      = w * 512;

    const int frow = lane & 15;
    const int cc   = (lane >> 4) ^ ((lane >> 1) & 3);
    const int aoff = (wr * 64 + frow) * 32 + cc * 8;
    const int boff = 4096 + (wc * 32 + frow) * 32 + cc * 8;

    f32x4 acc[4][2];
    #pragma unroll
    for (int mi = 0; mi < 4; ++mi)
        #pragma unroll
        for (int nj = 0; nj < 2; ++nj)
            acc[mi][nj] = (f32x4){0.f, 0.f, 0.f, 0.f};

    #define STAGEQ(srcA, srcB, slotp, koff)                                  \
        do {                                                                 \
            ushort* sl_ = (slotp);                                           \
            gl16((srcA) + rowA  + (koff), sl_ + wl);                         \
            gl16((srcA) + rowA2 + (koff), sl_ + 2048 + wl);                  \
            gl16((srcB) + rowB  + (koff), sl_ + 4096 + wl);                  \
        } while (0)

    // prologue: hi(0)->slot0, lo(0)->slot1, hi(1)->slot2  (9 loads in flight)
    STAGEQ(Ahi, Bhi, smem, 0);
    STAGEQ(Alo, Blo, smem + G1Q_SLOT, 0);
    STAGEQ(Ahi, Bhi, smem + 2 * G1Q_SLOT, 32);

    #pragma unroll 1
    for (int kt = 0; kt < 32; ++kt) {
        ushort* sh = smem + ((2 * kt) & 3) * G1Q_SLOT;      // hi(kt)
        ushort* sl = smem + ((2 * kt + 1) & 3) * G1Q_SLOT;  // lo(kt)
        ushort* nl = smem + ((2 * kt + 3) & 3) * G1Q_SLOT;  // lo(kt+1) dest
        const int kn1 = (kt + 1) * 32;
        const int kn2 = (kt + 2) * 32;

        bf16x8 ah[4], bh[2], bl[2], al[4];

        // ---- ph1: hi(kt) valid; stage lo(kt+1)
        if (kt < 31) { VMCNT(6); } else { VMCNT(3); }
        BAR;
        if (kt < 31) STAGEQ(Alo, Blo, nl, kn1);
        #pragma unroll
        for (int mi = 0; mi < 4; ++mi)
            ah[mi] = *(const bf16x8*)(sh + aoff + mi * 512);
        #pragma unroll
        for (int nj = 0; nj < 2; ++nj)
            bh[nj] = *(const bf16x8*)(sh + boff + nj * 512);
        __builtin_amdgcn_s_setprio(1);
        #pragma unroll
        for (int mi = 0; mi < 4; ++mi)
            #pragma unroll
            for (int nj = 0; nj < 2; ++nj)
                acc[mi][nj] = __builtin_amdgcn_mfma_f32_16x16x32_bf16(
                    ah[mi], bh[nj], acc[mi][nj], 0, 0, 0);
        __builtin_amdgcn_s_setprio(0);

        // ---- ph2: lo(kt) valid; stage hi(kt+2) into sh (ph1 reads landed)
        if (kt < 31) { VMCNT(6); } else { VMCNT(0); }
        BAR;
        if (kt < 30) STAGEQ(Ahi, Bhi, sh, kn2);
        #pragma unroll
        for (int nj = 0; nj < 2; ++nj)
            bl[nj] = *(const bf16x8*)(sl + boff + nj * 512);
        #pragma unroll
        for (int mi = 0; mi < 4; ++mi)
            al[mi] = *(const bf16x8*)(sl + aoff + mi * 512);
        __builtin_amdgcn_s_setprio(1);
        #pragma unroll
        for (int mi = 0; mi < 4; ++mi)
            #pragma unroll
            for (int nj = 0; nj < 2; ++nj)
                acc[mi][nj] = __builtin_amdgcn_mfma_f32_16x16x32_bf16(
                    ah[mi], bl[nj], acc[mi][nj], 0, 0, 0);
        __builtin_amdgcn_s_setprio(0);

        // ---- ph3: register-only
        __builtin_amdgcn_s_setprio(1);
        #pragma unroll
        for (int mi = 0; mi < 4; ++mi)
            #pragma unroll
            for (int nj = 0; nj < 2; ++nj)
                acc[mi][nj] = __builtin_amdgcn_mfma_f32_16x16x32_bf16(
                    al[mi], bh[nj], acc[mi][nj], 0, 0, 0);
        __builtin_amdgcn_s_setprio(0);
    }
    #undef STAGEQ

    const int erow  = m0 + wr * 64 + (lane >> 4) * 4;
    const int ecol0 = n0 + wc * 32 + frow;
    #pragma unroll
    for (int mi = 0; mi < 4; ++mi) {
        #pragma unroll
        for (int j = 0; j < 4; ++j) {
            const int row = erow + mi * 16 + j;
            #pragma unroll
            for (int nj = 0; nj < 2; ++nj) {
                const int col = ecol0 + nj * 16;
                dst[(size_t)row * 3072 + col] = elu1(acc[mi][nj][j]);
            }
        }
    }
}

// ---------------------------------------------------------------------------
// GEMM1KV: [K|V] = x @ Wkv^T, cols [1024,3072) of QKV; elu1 on col<2048.
// SINGLE-TERM bf16 (convexity: K/V bf16 errors average out in the
// normalized attention). 128x128 tile, 4 waves (2x2), wave 64x64.
// Grid 512 = 32m x 16n -> 2 blocks/CU (64KB). 1 barrier/kt, 4-slot rotation,
// depth-3 (4-load units, counted vmcnt(8); edges 4/0).
// ---------------------------------------------------------------------------
__global__ __launch_bounds__(256, 2)
void gemm1kv_kernel(const ushort* __restrict__ Ahi, const ushort* __restrict__ Bhi,
                    float* __restrict__ dst)
{
    __shared__ ushort smem[4 * G1KV_SLOT];   // 64 KB

    const int bid = blockIdx.x;
    const int wg  = (bid & 7) * 64 + (bid >> 3);    // bijective: 512 = 8*64
    const int m0  = (wg >> 4) * 128;                // 32 m-tiles
    const int nc  = (wg & 15) * 128;                // Wkv row base / col-1024

    const int t    = threadIdx.x;
    const int lane = t & 63;
    const int w    = t >> 6;
    const int wr   = w >> 1;       // 0..1
    const int wc   = w & 1;        // 0..1

    const int gch     = (t & 3) ^ ((t >> 3) & 3);
    const size_t rowA  = (size_t)(m0 + (t >> 2)) * KDIM + gch * 8;
    const size_t rowA2 = rowA + (size_t)64 * KDIM;
    const size_t rowB  = (size_t)(nc + (t >> 2)) * KDIM + gch * 8;
    const size_t rowB2 = rowB + (size_t)64 * KDIM;
    const int wl      = w * 512;

    const int frow = lane & 15;
    const int cc   = (lane >> 4) ^ ((lane >> 1) & 3);
    const int aoff = (wr * 64 + frow) * 32 + cc * 8;
    const int boff = 4096 + (wc * 64 + frow) * 32 + cc * 8;

    f32x4 acc[4][4];
    #pragma unroll
    for (int mi = 0; mi < 4; ++mi)
        #pragma unroll
        for (int nj = 0; nj < 4; ++nj)
            acc[mi][nj] = (f32x4){0.f, 0.f, 0.f, 0.f};

    #define STAGEKV(slotp, koff)                                             \
        do {                                                                 \
            ushort* sl_ = (slotp);                                           \
            gl16(Ahi + rowA  + (koff), sl_ + wl);                            \
            gl16(Ahi + rowA2 + (koff), sl_ + 2048 + wl);                     \
            gl16(Bhi + rowB  + (koff), sl_ + 4096 + wl);                     \
            gl16(Bhi + rowB2 + (koff), sl_ + 6144 + wl);                     \
        } while (0)

    // prologue: kt0->slot0, kt1->slot1, kt2->slot2  (12 loads in flight)
    STAGEKV(smem, 0);
    STAGEKV(smem + G1KV_SLOT, 32);
    STAGEKV(smem + 2 * G1KV_SLOT, 64);

    #pragma unroll 1
    for (int kt = 0; kt < 32; ++kt) {
        ushort* sh = smem + (kt & 3) * G1KV_SLOT;

        if (kt <= 29) { VMCNT(8); } else if (kt == 30) { VMCNT(4); } else { VMCNT(0); }
        BAR;   // all waves' kt-1 reads have landed; safe to overwrite slot (kt+3)&3 = (kt-1)&3
        if (kt <= 28) STAGEKV(smem + ((kt + 3) & 3) * G1KV_SLOT, (kt + 3) * 32);

        bf16x8 ah[4], bh[4];
        #pragma unroll
        for (int mi = 0; mi < 4; ++mi)
            ah[mi] = *(const bf16x8*)(sh + aoff + mi * 512);
        #pragma unroll
        for (int nj = 0; nj < 4; ++nj)
            bh[nj] = *(const bf16x8*)(sh + boff + nj * 512);
        __builtin_amdgcn_s_setprio(1);
        #pragma unroll
        for (int mi = 0; mi < 4; ++mi)
            #pragma unroll
            for (int nj = 0; nj < 4; ++nj)
                acc[mi][nj] = __builtin_amdgcn_mfma_f32_16x16x32_bf16(
                    ah[mi], bh[nj], acc[mi][nj], 0, 0, 0);
        __builtin_amdgcn_s_setprio(0);
    }
    #undef STAGEKV

    const int erow  = m0 + wr * 64 + (lane >> 4) * 4;
    const int ecol0 = 1024 + nc + wc * 64 + frow;
    #pragma unroll
    for (int mi = 0; mi < 4; ++mi) {
        #pragma unroll
        for (int j = 0; j < 4; ++j) {
            const int row = erow + mi * 16 + j;
            #pragma unroll
            for (int nj = 0; nj < 4; ++nj) {
                const int col = ecol0 + nj * 16;
                float v = acc[mi][nj][j];
                if (col < 2048) v = elu1(v);   // K gets elu1, V raw
                dst[(size_t)row * 3072 + col] = v;
            }
        }
    }
}

// ---------------------------------------------------------------------------
// GEMM2: out = O1 @ Wo^T + bo. 128x128 tile, BK=32, 8 waves (2M x 4N),
// wave tile 64x32. Grid 256 full fill. 3-phase depth-3 (vmcnt(4)/2/0). 64KB.
// ---------------------------------------------------------------------------
__global__ __launch_bounds__(512, 2)
void gemm2_mfma_kernel(const ushort* __restrict__ Ahi, const ushort* __restrict__ Alo,
                       const ushort* __restrict__ Bhi, const ushort* __restrict__ Blo,
                       const float* __restrict__ bias, float* __restrict__ dst)
{
    __shared__ ushort smem[4 * G2_SLOT];   // 64 KB

    const int bid = blockIdx.x;
    const int wg  = (bid & 7) * 32 + (bid >> 3);    // bijective: 256 = 8*32
    const int m0  = (wg >> 3) * 128;
    const int n0  = (wg & 7) * 128;

    const int t    = threadIdx.x;
    const int lane = t & 63;
    const int w    = t >> 6;      // 0..7
    const int wr   = w >> 2;      // 0..1
    const int wc   = w & 3;       // 0..3

    const int gch     = (t & 3) ^ ((t >> 3) & 3);
    const size_t rowA = (size_t)(m0 + (t >> 2)) * KDIM + gch * 8;
    const size_t rowB = (size_t)(n0 + (t >> 2)) * KDIM + gch * 8;
    const int wl      = w * 512;

    const int frow = lane & 15;
    const int cc   = (lane >> 4) ^ ((lane >> 1) & 3);
    const int aoff = (wr * 64 + frow) * 32 + cc * 8;
    const int boff = 4096 + (wc * 32 + frow) * 32 + cc * 8;

    f32x4 acc[4][2];
    #pragma unroll
    for (int mi = 0; mi < 4; ++mi)
        #pragma unroll
        for (int nj = 0; nj < 2; ++nj)
            acc[mi][nj] = (f32x4){0.f, 0.f, 0.f, 0.f};

    #define STAGE2(srcA, srcB, slotp, koff)                                  \
        do {                                                                 \
            ushort* p_ = (slotp);                                            \
            gl16((srcA) + rowA + (koff), p_ + wl);                           \
            gl16((srcB) + rowB + (koff), p_ + 4096 + wl);                    \
        } while (0)

    STAGE2(Ahi, Bhi, smem, 0);
    STAGE2(Alo, Blo, smem + G2_SLOT, 0);
    STAGE2(Ahi, Bhi, smem + 2 * G2_SLOT, 32);

    #pragma unroll 1
    for (int kt = 0; kt < 32; ++kt) {
        ushort* sh = smem + ((2 * kt) & 3) * G2_SLOT;
        ushort* sl = smem + ((2 * kt + 1) & 3) * G2_SLOT;
        ushort* nl = smem + ((2 * kt + 3) & 3) * G2_SLOT;
        const int kn1 = (kt + 1) * 32;
        const int kn2 = (kt + 2) * 32;

        bf16x8 ah[4], bh[2], bl[2], al[4];

        // ---- ph1: hh
        if (kt < 31) { VMCNT(4); } else { VMCNT(2); }
        BAR;
        if (kt < 31) STAGE2(Alo, Blo, nl, kn1);
        #pragma unroll
        for (int mi = 0; mi < 4; ++mi)
            ah[mi] = *(const bf16x8*)(sh + aoff + mi * 512);
        #pragma unroll
        for (int nj = 0; nj < 2; ++nj)
            bh[nj] = *(const bf16x8*)(sh + boff + nj * 512);
        __builtin_amdgcn_s_setprio(1);
        #pragma unroll
        for (int mi = 0; mi < 4; ++mi)
            #pragma unroll
            for (int nj = 0; nj < 2; ++nj)
                acc[mi][nj] = __builtin_amdgcn_mfma_f32_16x16x32_bf16(
                    ah[mi], bh[nj], acc[mi][nj], 0, 0, 0);
        __builtin_amdgcn_s_setprio(0);

        // ---- ph2: hl
        if (kt < 31) { VMCNT(4); } else { VMCNT(0); }
        BAR;
        if (kt < 30) STAGE2(Ahi, Bhi, sh, kn2);
        #pragma unroll
        for (int nj = 0; nj < 2; ++nj)
            bl[nj] = *(const bf16x8*)(sl + boff + nj * 512);
        #pragma unroll
        for (int mi = 0; mi < 4; ++mi)
            al[mi] = *(const bf16x8*)(sl + aoff + mi * 512);
        __builtin_amdgcn_s_setprio(1);
        #pragma unroll
        for (int mi = 0; mi < 4; ++mi)
            #pragma unroll
            for (int nj = 0; nj < 2; ++nj)
                acc[mi][nj] = __builtin_amdgcn_mfma_f32_16x16x32_bf16(
                    ah[mi], bl[nj], acc[mi][nj], 0, 0, 0);
        __builtin_amdgcn_s_setprio(0);

        // ---- ph3: lh (register-only)
        __builtin_amdgcn_s_setprio(1);
        #pragma unroll
        for (int mi = 0; mi < 4; ++mi)
            #pragma unroll
            for (int nj = 0; nj < 2; ++nj)
                acc[mi][nj] = __builtin_amdgcn_mfma_f32_16x16x32_bf16(
                    al[mi], bh[nj], acc[mi][nj], 0, 0, 0);
        __builtin_amdgcn_s_setprio(0);
    }
    #undef STAGE2

    const int erow  = m0 + wr * 64 + (lane >> 4) * 4;
    const int ecol0 = n0 + wc * 32 + frow;
    #pragma unroll
    for (int mi = 0; mi < 4; ++mi) {
        #pragma unroll
        for (int j = 0; j < 4; ++j) {
            const int row = erow + mi * 16 + j;
            #pragma unroll
            for (int nj = 0; nj < 2; ++nj) {
                const int col = ecol0 + nj * 16;
                dst[(size_t)row * 1024 + col] = acc[mi][nj][j] + bias[col];
            }
        }
    }
}

// ---------------------------------------------------------------------------
// Partial KV = K_feat^T V and ksum, per (b,h), 8-way N split (256 rows each).
// ---------------------------------------------------------------------------
__global__ __launch_bounds__(256)
void kv_partial_kernel(const float* __restrict__ QKV, float* __restrict__ KVp)
{
    const int bh = blockIdx.x;   // 0..31
    const int s  = blockIdx.y;   // 0..7
    const int b  = bh >> 4;
    const int h  = bh & 15;
    const int t  = threadIdx.x;

    __shared__ float ks[16][64];
    __shared__ float vs[16][64];
    __shared__ float red[4160];

    const int srow = t >> 4;
    const int scol = (t & 15) * 4;
    const size_t gk = (size_t)(b * N_SEQ + s * 256) * 3072 + 1024 + h * 64 + scol;
    const size_t gv = gk + 1024;

    const int rs = t >> 6;
    const int dg = (t >> 3) & 7;
    const int eg = t & 7;
    const int d0 = dg * 8;
    const int e0 = eg * 8;

    float acc[8][8];
    #pragma unroll
    for (int i = 0; i < 8; ++i)
        #pragma unroll
        for (int j = 0; j < 8; ++j) acc[i][j] = 0.f;
    float aks[8] = {0.f, 0.f, 0.f, 0.f, 0.f, 0.f, 0.f, 0.f};

    float4 kr = *(const float4*)&QKV[gk + (size_t)srow * 3072];
    float4 vr = *(const float4*)&QKV[gv + (size_t)srow * 3072];

    for (int it = 0; it < 16; ++it) {
        __syncthreads();
        *(float4*)&ks[srow][scol] = kr;
        *(float4*)&vs[srow][scol] = vr;
        __syncthreads();
        if (it < 15) {
            kr = *(const float4*)&QKV[gk + (size_t)((it + 1) * 16 + srow) * 3072];
            vr = *(const float4*)&QKV[gv + (size_t)((it + 1) * 16 + srow) * 3072];
        }
        #pragma unroll
        for (int rr = 0; rr < 4; ++rr) {
            const int r = rs * 4 + rr;
            const float4 ka = *(const float4*)&ks[r][d0];
            const float4 kb = *(const float4*)&ks[r][d0 + 4];
            const float4 va = *(const float4*)&vs[r][e0];
            const float4 vb = *(const float4*)&vs[r][e0 + 4];
            const float k8[8] = {ka.x, ka.y, ka.z, ka.w, kb.x, kb.y, kb.z, kb.w};
            const float v8[8] = {va.x, va.y, va.z, va.w, vb.x, vb.y, vb.z, vb.w};
            #pragma unroll
            for (int i = 0; i < 8; ++i)
                #pragma unroll
                for (int j = 0; j < 8; ++j)
                    acc[i][j] += k8[i] * v8[j];
            if (eg == 0) {
                #pragma unroll
                for (int i = 0; i < 8; ++i) aks[i] += k8[i];
            }
        }
    }

    #pragma unroll 1
    for (int step = 1; step < 4; ++step) {
        __syncthreads();
        if (rs == step) {
            #pragma unroll
            for (int i = 0; i < 8; ++i)
                #pragma unroll
                for (int j = 0; j < 8; ++j)
                    red[(d0 + i) * 64 + e0 + j] = acc[i][j];
            if (eg == 0) {
                #pragma unroll
                for (int i = 0; i < 8; ++i) red[4096 + d0 + i] = aks[i];
            }
        }
        __syncthreads();
        if (rs == 0) {
            #pragma unroll
            for (int i = 0; i < 8; ++i)
                #pragma unroll
                for (int j = 0; j < 8; ++j)
                    acc[i][j] += red[(d0 + i) * 64 + e0 + j];
            if (eg == 0) {
                #pragma unroll
                for (int i = 0; i < 8; ++i) aks[i] += red[4096 + d0 + i];
            }
        }
    }

    if (rs == 0) {
        float* outp = KVp + ((size_t)s * 32 + bh) * 4160;
        #pragma unroll
        for (int i = 0; i < 8; ++i) {
            float4 o0 = {acc[i][0], acc[i][1], acc[i][2], acc[i][3]};
            float4 o1 = {acc[i][4], acc[i][5], acc[i][6], acc[i][7]};
            *(float4*)(outp + (d0 + i) * 64 + e0)     = o0;
            *(float4*)(outp + (d0 + i) * 64 + e0 + 4) = o1;
        }
        if (eg == 0) {
            #pragma unroll
            for (int i = 0; i < 8; ++i) outp[4096 + d0 + i] = aks[i];
        }
    }
}

__global__ __launch_bounds__(256)
void kv_reduce_kernel(const float* __restrict__ KVp, float* __restrict__ KVf)
{
    const int idx = blockIdx.x * 256 + threadIdx.x;
    if (idx < 32 * 4160) {
        float s = 0.f;
        #pragma unroll
        for (int i = 0; i < 8; ++i) s += KVp[(size_t)i * (32 * 4160) + idx];
        KVf[idx] = s;
    }
}

// ---------------------------------------------------------------------------
// O1[n, h*64+e] = Z * sum_d q[n,d]*KV[d,e], Z = 1/(q.ksum + 1e-6); bf16 hi/lo out
// ---------------------------------------------------------------------------
__global__ __launch_bounds__(256)
void attn_apply_kernel(const float* __restrict__ QKV, const float* __restrict__ KVf,
                       ushort* __restrict__ O1hi, ushort* __restrict__ O1lo)
{
    const int bh = blockIdx.x;
    const int b = bh >> 4, h = bh & 15;
    const int n0 = blockIdx.y * 16;
    const int t = threadIdx.x;
    const int r  = t >> 4;
    const int e0 = (t & 15) * 4;

    __shared__ float kvs[64][68];
    __shared__ float qs[16][68];
    __shared__ float ksums[64];

    const float* kvb = KVf + (size_t)bh * 4160;
    for (int i = t; i < 4096; i += 256)
        kvs[i >> 6][i & 63] = kvb[i];
    if (t < 64) ksums[t] = kvb[4096 + t];
    {
        const int rr = t >> 4, cc2 = (t & 15) * 4;
        *(float4*)&qs[rr][cc2] =
            *(const float4*)&QKV[(size_t)(b * N_SEQ + n0 + rr) * 3072 + h * 64 + cc2];
    }
    __syncthreads();

    float4 acc = {0.f, 0.f, 0.f, 0.f};
    float accz = 0.f;
    #pragma unroll
    for (int d = 0; d < 64; ++d) {
        const float qv = qs[r][d];
        const float4 kvv = *(const float4*)&kvs[d][e0];
        acc.x += qv * kvv.x; acc.y += qv * kvv.y;
        acc.z += qv * kvv.z; acc.w += qv * kvv.w;
        accz += qv * ksums[d];
    }
    const float Z = 1.f / (accz + 1e-6f);
    const float vv[4] = {acc.x * Z, acc.y * Z, acc.z * Z, acc.w * Z};
    ushort hv[4], lv[4];
    #pragma unroll
    for (int j = 0; j < 4; ++j) {
        hv[j] = f2bf(vv[j]);
        lv[j] = f2bf(vv[j] - bf2f(hv[j]));
    }
    const size_t off = (size_t)(b * N_SEQ + n0 + r) * C_DIM + h * 64 + e0;
    short4v H = {(short)hv[0], (short)hv[1], (short)hv[2], (short)hv[3]};
    short4v L = {(short)lv[0], (short)lv[1], (short)lv[2], (short)lv[3]};
    *(short4v*)&O1hi[off] = H;
    *(short4v*)&O1lo[off] = L;
}

extern "C" void kernel_launch(void* const* d_in, const int* in_sizes, int n_in,
                              void* d_out, int out_size, void* d_ws, size_t ws_size,
                              hipStream_t stream)
{
    const float* x   = (const float*)d_in[0];
    const float* Wq  = (const float*)d_in[1];
    const float* Wkv = (const float*)d_in[2];
    const float* Wo  = (const float*)d_in[3];
    const float* bo  = (const float*)d_in[4];
    float* out = (float*)d_out;

    float* ws   = (float*)d_ws;
    float* QKV  = ws;                                  // 4096*3072 f32
    float* KVp  = QKV + (size_t)M_ROWS * 3072;         // 8*32*4160
    float* KVf  = KVp + (size_t)8 * 32 * 4160;         // 32*4160
    ushort* xhi = (ushort*)(KVf + 32 * 4160);          // 4096*1024 bf16 each
    ushort* xlo = xhi + (size_t)M_ROWS * 1024;
    ushort* Whi = xlo + (size_t)M_ROWS * 1024;         // 3072*1024 (Wq;Wkv)
    ushort* Wlo = Whi + (size_t)3072 * 1024;
    ushort* Wohi = Wlo + (size_t)3072 * 1024;          // 1024*1024
    ushort* Wolo = Wohi + (size_t)1024 * 1024;
    ushort* O1hi = xhi;                                // alias: x dead after GEMM1
    ushort* O1lo = xlo;

    // 0. split fp32 -> bf16 hi/lo
    split_all_kernel<<<dim3(4096), 256, 0, stream>>>(
        x, Wq, Wkv, Wo, xhi, xlo, Whi, Wlo, Wohi, Wolo);

    // 1a. Q projection (3-term) + elu1
    gemm1q_kernel<<<dim3(512), 256, 0, stream>>>(xhi, xlo, Whi, Wlo, QKV);

    // 1b. K|V projection (1-term bf16; error averages out in normalized attn)
    gemm1kv_kernel<<<dim3(512), 256, 0, stream>>>(
        xhi, Whi + (size_t)1024 * 1024, QKV);

    // 2-3. KV = K^T V + ksum (8-way split + deterministic reduce)
    kv_partial_kernel<<<dim3(32, 8), 256, 0, stream>>>(QKV, KVp);
    kv_reduce_kernel<<<dim3((32 * 4160 + 255) / 256), 256, 0, stream>>>(KVp, KVf);

    // 4. O1 = Z * (q @ KV), bf16 hi/lo out
    attn_apply_kernel<<<dim3(32, 128), 256, 0, stream>>>(QKV, KVf, O1hi, O1lo);

    // 5. final projection + bias
    gemm2_mfma_kernel<<<dim3(256), 512, 0, stream>>>(O1hi, O1lo, Wohi, Wolo, bo, out);
}

// Round 15
// 112.573 us; speedup vs baseline: 1.3765x; 1.2363x over previous
//
#include <hip/hip_runtime.h>
#include <math.h>

#define C_DIM 1024
#define B_SZ 2
#define N_SEQ 2048
#define M_ROWS (B_SZ * N_SEQ)   // 4096
#define KDIM 1024
#define G1_SLOT 10240           // ushorts per 20KB gemm1 slot (A 8KB + B 12KB)
#define G2_SLOT 8192            // ushorts per 16KB gemm2 slot

typedef float  f32x4   __attribute__((ext_vector_type(4)));
typedef short  bf16x8  __attribute__((ext_vector_type(8)));
typedef short  short4v __attribute__((ext_vector_type(4)));
typedef short  short8v __attribute__((ext_vector_type(8)));

__device__ __forceinline__ float elu1(float v) {
    return v > 0.f ? v + 1.f : expf(v);
}

__device__ __forceinline__ ushort f2bf(float f) {
    union { float f; unsigned u; } x; x.f = f;
    unsigned r = (x.u + 0x7fffu + ((x.u >> 16) & 1u)) >> 16;  // RNE
    return (ushort)r;
}
__device__ __forceinline__ float bf2f(ushort b) {
    union { unsigned u; float f; } x; x.u = ((unsigned)b) << 16;
    return x.f;
}

#define VMCNT(n) asm volatile("s_waitcnt vmcnt(" #n ")" ::: "memory")
// Fence + barrier: guarantee every wave's outstanding LDS reads are DELIVERED
// before any wave passes the barrier (compiler may otherwise sink the MFMA
// lgkm waits past a raw s_barrier -> slot-overwrite race, R14 failure).
#define LGKMBAR do {                                                  \
        asm volatile("s_waitcnt lgkmcnt(0)" ::: "memory");            \
        __builtin_amdgcn_sched_barrier(0);                            \
        __builtin_amdgcn_s_barrier();                                 \
    } while (0)

__device__ __forceinline__ void gl16(const ushort* g, ushort* l) {
    __builtin_amdgcn_global_load_lds(
        (const __attribute__((address_space(1))) unsigned int*)g,
        (__attribute__((address_space(3))) unsigned int*)l,
        16, 0, 0);
}

// ---------------------------------------------------------------------------
// fp32 -> bf16 split. x and W(q|kv): hi only (1-term consumers).
// Wo: hi+lo (gemm2 stays 3-term). 8 elems/thread.
// ---------------------------------------------------------------------------
__global__ __launch_bounds__(256)
void split_all_kernel(const float* __restrict__ x, const float* __restrict__ Wq,
                      const float* __restrict__ Wkv, const float* __restrict__ Wo,
                      ushort* __restrict__ xhi, ushort* __restrict__ Whi,
                      ushort* __restrict__ Wohi, ushort* __restrict__ Wolo)
{
    const int i = blockIdx.x * 256 + threadIdx.x;   // 0..1048575
    const float* src; ushort* dh; ushort* dl = nullptr; int off;
    if (i < 524288)        { src = x;   dh = xhi;  off = i; }
    else if (i < 655360)   { src = Wq;  dh = Whi;  off = i - 524288; }
    else if (i < 917504)   { src = Wkv; dh = Whi + (1u << 20); off = i - 655360; }
    else                   { src = Wo;  dh = Wohi; dl = Wolo; off = i - 917504; }

    const float4 a = ((const float4*)src)[off * 2];
    const float4 b = ((const float4*)src)[off * 2 + 1];
    const float v[8] = {a.x, a.y, a.z, a.w, b.x, b.y, b.z, b.w};
    ushort hv[8];
    #pragma unroll
    for (int j = 0; j < 8; ++j) hv[j] = f2bf(v[j]);
    short8v H = {(short)hv[0],(short)hv[1],(short)hv[2],(short)hv[3],
                 (short)hv[4],(short)hv[5],(short)hv[6],(short)hv[7]};
    *(short8v*)&dh[(size_t)off * 8] = H;
    if (dl) {
        ushort lv[8];
        #pragma unroll
        for (int j = 0; j < 8; ++j) lv[j] = f2bf(v[j] - bf2f(hv[j]));
        short8v L = {(short)lv[0],(short)lv[1],(short)lv[2],(short)lv[3],
                     (short)lv[4],(short)lv[5],(short)lv[6],(short)lv[7]};
        *(short8v*)&dl[(size_t)off * 8] = L;
    }
}

// ---------------------------------------------------------------------------
// GEMM1: QKV = x @ [Wq;Wkv]^T (all 3072 cols), SINGLE-TERM bf16.
// 128x192 tile, BK=32, 4 waves (2x2), wave 64x96. Grid 512 -> 2 blocks/CU
// (80KB LDS). 1 barrier/kt (LGKMBAR-fenced), 4-slot rotation, depth-3
// (5-load units, counted vmcnt(10); edges 5/0). elu1 on cols<2048; V raw.
// ---------------------------------------------------------------------------
__global__ __launch_bounds__(256, 2)
void gemm1_kernel(const ushort* __restrict__ Ahi, const ushort* __restrict__ Bhi,
                  float* __restrict__ dst)
{
    extern __shared__ ushort smem[];   // 4 slots x 10240 ushorts (80 KB)

    const int bid = blockIdx.x;
    const int wg  = (bid & 7) * 64 + (bid >> 3);    // bijective: 512 = 8*64
    const int m0  = (wg >> 4) * 128;                // 32 m-tiles
    const int n0  = (wg & 15) * 192;                // 16 n-tiles

    const int t    = threadIdx.x;
    const int lane = t & 63;
    const int w    = t >> 6;       // 0..3
    const int wr   = w >> 1;       // 0..1  (M half, 64 rows)
    const int wc   = w & 1;        // 0..1  (N half, 96 cols)

    const int gch     = (t & 3) ^ ((t >> 3) & 3);
    const size_t rowA  = (size_t)(m0 + (t >> 2)) * KDIM + gch * 8;   // A rows 0..63
    const size_t rowA2 = rowA + (size_t)64 * KDIM;                   // 64..127
    const size_t rowB  = (size_t)(n0 + (t >> 2)) * KDIM + gch * 8;   // B rows 0..63
    const size_t rowB2 = rowB + (size_t)64 * KDIM;                   // 64..127
    const size_t rowB3 = rowB + (size_t)128 * KDIM;                  // 128..191
    const int wl      = w * 512;

    const int frow = lane & 15;
    const int cc   = (lane >> 4) ^ ((lane >> 1) & 3);
    const int aoff = (wr * 64 + frow) * 32 + cc * 8;
    const int boff = 4096 + (wc * 96 + frow) * 32 + cc * 8;

    f32x4 acc[4][6];
    #pragma unroll
    for (int mi = 0; mi < 4; ++mi)
        #pragma unroll
        for (int nj = 0; nj < 6; ++nj)
            acc[mi][nj] = (f32x4){0.f, 0.f, 0.f, 0.f};

    #define STAGE1(slotp, koff)                                              \
        do {                                                                 \
            ushort* sl_ = (slotp);                                           \
            gl16(Ahi + rowA  + (koff), sl_ + wl);                            \
            gl16(Ahi + rowA2 + (koff), sl_ + 2048 + wl);                     \
            gl16(Bhi + rowB  + (koff), sl_ + 4096 + wl);                     \
            gl16(Bhi + rowB2 + (koff), sl_ + 6144 + wl);                     \
            gl16(Bhi + rowB3 + (koff), sl_ + 8192 + wl);                     \
        } while (0)

    // prologue: kt0->slot0, kt1->slot1, kt2->slot2  (15 loads in flight)
    STAGE1(smem, 0);
    STAGE1(smem + G1_SLOT, 32);
    STAGE1(smem + 2 * G1_SLOT, 64);

    #pragma unroll 1
    for (int kt = 0; kt < 32; ++kt) {
        ushort* sh = smem + (kt & 3) * G1_SLOT;

        if (kt <= 29) { VMCNT(10); } else if (kt == 30) { VMCNT(5); } else { VMCNT(0); }
        LGKMBAR;   // all waves' kt-1 reads DELIVERED before slot reuse
        if (kt <= 28) STAGE1(smem + ((kt + 3) & 3) * G1_SLOT, (kt + 3) * 32);

        bf16x8 ah[4], bh[6];
        #pragma unroll
        for (int mi = 0; mi < 4; ++mi)
            ah[mi] = *(const bf16x8*)(sh + aoff + mi * 512);
        #pragma unroll
        for (int nj = 0; nj < 6; ++nj)
            bh[nj] = *(const bf16x8*)(sh + boff + nj * 512);
        __builtin_amdgcn_s_setprio(1);
        #pragma unroll
        for (int mi = 0; mi < 4; ++mi)
            #pragma unroll
            for (int nj = 0; nj < 6; ++nj)
                acc[mi][nj] = __builtin_amdgcn_mfma_f32_16x16x32_bf16(
                    ah[mi], bh[nj], acc[mi][nj], 0, 0, 0);
        __builtin_amdgcn_s_setprio(0);
    }
    #undef STAGE1

    const int erow  = m0 + wr * 64 + (lane >> 4) * 4;
    const int ecol0 = n0 + wc * 96 + frow;
    #pragma unroll
    for (int mi = 0; mi < 4; ++mi) {
        #pragma unroll
        for (int j = 0; j < 4; ++j) {
            const int row = erow + mi * 16 + j;
            #pragma unroll
            for (int nj = 0; nj < 6; ++nj) {
                const int col = ecol0 + nj * 16;
                float v = acc[mi][nj][j];
                if (col < 2048) v = elu1(v);   // Q,K get elu1; V raw
                dst[(size_t)row * 3072 + col] = v;
            }
        }
    }
}

// ---------------------------------------------------------------------------
// GEMM2: out = O1 @ Wo^T + bo. 3-term split-bf16. 128x128 tile, BK=32,
// 8 waves (2M x 4N), wave tile 64x32. Grid 256 full fill. 3-phase depth-3
// (vmcnt(4)/2/0), LGKMBAR-fenced barriers. 64KB LDS.
// ---------------------------------------------------------------------------
__global__ __launch_bounds__(512, 2)
void gemm2_mfma_kernel(const ushort* __restrict__ Ahi, const ushort* __restrict__ Alo,
                       const ushort* __restrict__ Bhi, const ushort* __restrict__ Blo,
                       const float* __restrict__ bias, float* __restrict__ dst)
{
    __shared__ ushort smem[4 * G2_SLOT];   // 64 KB

    const int bid = blockIdx.x;
    const int wg  = (bid & 7) * 32 + (bid >> 3);    // bijective: 256 = 8*32
    const int m0  = (wg >> 3) * 128;
    const int n0  = (wg & 7) * 128;

    const int t    = threadIdx.x;
    const int lane = t & 63;
    const int w    = t >> 6;      // 0..7
    const int wr   = w >> 2;      // 0..1
    const int wc   = w & 3;       // 0..3

    const int gch     = (t & 3) ^ ((t >> 3) & 3);
    const size_t rowA = (size_t)(m0 + (t >> 2)) * KDIM + gch * 8;
    const size_t rowB = (size_t)(n0 + (t >> 2)) * KDIM + gch * 8;
    const int wl      = w * 512;

    const int frow = lane & 15;
    const int cc   = (lane >> 4) ^ ((lane >> 1) & 3);
    const int aoff = (wr * 64 + frow) * 32 + cc * 8;
    const int boff = 4096 + (wc * 32 + frow) * 32 + cc * 8;

    f32x4 acc[4][2];
    #pragma unroll
    for (int mi = 0; mi < 4; ++mi)
        #pragma unroll
        for (int nj = 0; nj < 2; ++nj)
            acc[mi][nj] = (f32x4){0.f, 0.f, 0.f, 0.f};

    #define STAGE2(srcA, srcB, slotp, koff)                                  \
        do {                                                                 \
            ushort* p_ = (slotp);                                            \
            gl16((srcA) + rowA + (koff), p_ + wl);                           \
            gl16((srcB) + rowB + (koff), p_ + 4096 + wl);                    \
        } while (0)

    STAGE2(Ahi, Bhi, smem, 0);
    STAGE2(Alo, Blo, smem + G2_SLOT, 0);
    STAGE2(Ahi, Bhi, smem + 2 * G2_SLOT, 32);

    #pragma unroll 1
    for (int kt = 0; kt < 32; ++kt) {
        ushort* sh = smem + ((2 * kt) & 3) * G2_SLOT;
        ushort* sl = smem + ((2 * kt + 1) & 3) * G2_SLOT;
        ushort* nl = smem + ((2 * kt + 3) & 3) * G2_SLOT;
        const int kn1 = (kt + 1) * 32;
        const int kn2 = (kt + 2) * 32;

        bf16x8 ah[4], bh[2], bl[2], al[4];

        // ---- ph1: hh
        if (kt < 31) { VMCNT(4); } else { VMCNT(2); }
        LGKMBAR;
        if (kt < 31) STAGE2(Alo, Blo, nl, kn1);
        #pragma unroll
        for (int mi = 0; mi < 4; ++mi)
            ah[mi] = *(const bf16x8*)(sh + aoff + mi * 512);
        #pragma unroll
        for (int nj = 0; nj < 2; ++nj)
            bh[nj] = *(const bf16x8*)(sh + boff + nj * 512);
        __builtin_amdgcn_s_setprio(1);
        #pragma unroll
        for (int mi = 0; mi < 4; ++mi)
            #pragma unroll
            for (int nj = 0; nj < 2; ++nj)
                acc[mi][nj] = __builtin_amdgcn_mfma_f32_16x16x32_bf16(
                    ah[mi], bh[nj], acc[mi][nj], 0, 0, 0);
        __builtin_amdgcn_s_setprio(0);

        // ---- ph2: hl
        if (kt < 31) { VMCNT(4); } else { VMCNT(0); }
        LGKMBAR;
        if (kt < 30) STAGE2(Ahi, Bhi, sh, kn2);
        #pragma unroll
        for (int nj = 0; nj < 2; ++nj)
            bl[nj] = *(const bf16x8*)(sl + boff + nj * 512);
        #pragma unroll
        for (int mi = 0; mi < 4; ++mi)
            al[mi] = *(const bf16x8*)(sl + aoff + mi * 512);
        __builtin_amdgcn_s_setprio(1);
        #pragma unroll
        for (int mi = 0; mi < 4; ++mi)
            #pragma unroll
            for (int nj = 0; nj < 2; ++nj)
                acc[mi][nj] = __builtin_amdgcn_mfma_f32_16x16x32_bf16(
                    ah[mi], bl[nj], acc[mi][nj], 0, 0, 0);
        __builtin_amdgcn_s_setprio(0);

        // ---- ph3: lh (register-only)
        __builtin_amdgcn_s_setprio(1);
        #pragma unroll
        for (int mi = 0; mi < 4; ++mi)
            #pragma unroll
            for (int nj = 0; nj < 2; ++nj)
                acc[mi][nj] = __builtin_amdgcn_mfma_f32_16x16x32_bf16(
                    al[mi], bh[nj], acc[mi][nj], 0, 0, 0);
        __builtin_amdgcn_s_setprio(0);
    }
    #undef STAGE2

    const int erow  = m0 + wr * 64 + (lane >> 4) * 4;
    const int ecol0 = n0 + wc * 32 + frow;
    #pragma unroll
    for (int mi = 0; mi < 4; ++mi) {
        #pragma unroll
        for (int j = 0; j < 4; ++j) {
            const int row = erow + mi * 16 + j;
            #pragma unroll
            for (int nj = 0; nj < 2; ++nj) {
                const int col = ecol0 + nj * 16;
                dst[(size_t)row * 1024 + col] = acc[mi][nj][j] + bias[col];
            }
        }
    }
}

// ---------------------------------------------------------------------------
// Partial KV = K_feat^T V and ksum, per (b,h), 8-way N split (256 rows each).
// ---------------------------------------------------------------------------
__global__ __launch_bounds__(256)
void kv_partial_kernel(const float* __restrict__ QKV, float* __restrict__ KVp)
{
    const int bh = blockIdx.x;   // 0..31
    const int s  = blockIdx.y;   // 0..7
    const int b  = bh >> 4;
    const int h  = bh & 15;
    const int t  = threadIdx.x;

    __shared__ float ks[16][64];
    __shared__ float vs[16][64];
    __shared__ float red[4160];

    const int srow = t >> 4;
    const int scol = (t & 15) * 4;
    const size_t gk = (size_t)(b * N_SEQ + s * 256) * 3072 + 1024 + h * 64 + scol;
    const size_t gv = gk + 1024;

    const int rs = t >> 6;
    const int dg = (t >> 3) & 7;
    const int eg = t & 7;
    const int d0 = dg * 8;
    const int e0 = eg * 8;

    float acc[8][8];
    #pragma unroll
    for (int i = 0; i < 8; ++i)
        #pragma unroll
        for (int j = 0; j < 8; ++j) acc[i][j] = 0.f;
    float aks[8] = {0.f, 0.f, 0.f, 0.f, 0.f, 0.f, 0.f, 0.f};

    float4 kr = *(const float4*)&QKV[gk + (size_t)srow * 3072];
    float4 vr = *(const float4*)&QKV[gv + (size_t)srow * 3072];

    for (int it = 0; it < 16; ++it) {
        __syncthreads();
        *(float4*)&ks[srow][scol] = kr;
        *(float4*)&vs[srow][scol] = vr;
        __syncthreads();
        if (it < 15) {
            kr = *(const float4*)&QKV[gk + (size_t)((it + 1) * 16 + srow) * 3072];
            vr = *(const float4*)&QKV[gv + (size_t)((it + 1) * 16 + srow) * 3072];
        }
        #pragma unroll
        for (int rr = 0; rr < 4; ++rr) {
            const int r = rs * 4 + rr;
            const float4 ka = *(const float4*)&ks[r][d0];
            const float4 kb = *(const float4*)&ks[r][d0 + 4];
            const float4 va = *(const float4*)&vs[r][e0];
            const float4 vb = *(const float4*)&vs[r][e0 + 4];
            const float k8[8] = {ka.x, ka.y, ka.z, ka.w, kb.x, kb.y, kb.z, kb.w};
            const float v8[8] = {va.x, va.y, va.z, va.w, vb.x, vb.y, vb.z, vb.w};
            #pragma unroll
            for (int i = 0; i < 8; ++i)
                #pragma unroll
                for (int j = 0; j < 8; ++j)
                    acc[i][j] += k8[i] * v8[j];
            if (eg == 0) {
                #pragma unroll
                for (int i = 0; i < 8; ++i) aks[i] += k8[i];
            }
        }
    }

    #pragma unroll 1
    for (int step = 1; step < 4; ++step) {
        __syncthreads();
        if (rs == step) {
            #pragma unroll
            for (int i = 0; i < 8; ++i)
                #pragma unroll
                for (int j = 0; j < 8; ++j)
                    red[(d0 + i) * 64 + e0 + j] = acc[i][j];
            if (eg == 0) {
                #pragma unroll
                for (int i = 0; i < 8; ++i) red[4096 + d0 + i] = aks[i];
            }
        }
        __syncthreads();
        if (rs == 0) {
            #pragma unroll
            for (int i = 0; i < 8; ++i)
                #pragma unroll
                for (int j = 0; j < 8; ++j)
                    acc[i][j] += red[(d0 + i) * 64 + e0 + j];
            if (eg == 0) {
                #pragma unroll
                for (int i = 0; i < 8; ++i) aks[i] += red[4096 + d0 + i];
            }
        }
    }

    if (rs == 0) {
        float* outp = KVp + ((size_t)s * 32 + bh) * 4160;
        #pragma unroll
        for (int i = 0; i < 8; ++i) {
            float4 o0 = {acc[i][0], acc[i][1], acc[i][2], acc[i][3]};
            float4 o1 = {acc[i][4], acc[i][5], acc[i][6], acc[i][7]};
            *(float4*)(outp + (d0 + i) * 64 + e0)     = o0;
            *(float4*)(outp + (d0 + i) * 64 + e0 + 4) = o1;
        }
        if (eg == 0) {
            #pragma unroll
            for (int i = 0; i < 8; ++i) outp[4096 + d0 + i] = aks[i];
        }
    }
}

__global__ __launch_bounds__(256)
void kv_reduce_kernel(const float* __restrict__ KVp, float* __restrict__ KVf)
{
    const int idx = blockIdx.x * 256 + threadIdx.x;
    if (idx < 32 * 4160) {
        float s = 0.f;
        #pragma unroll
        for (int i = 0; i < 8; ++i) s += KVp[(size_t)i * (32 * 4160) + idx];
        KVf[idx] = s;
    }
}

// ---------------------------------------------------------------------------
// O1[n, h*64+e] = Z * sum_d q[n,d]*KV[d,e], Z = 1/(q.ksum + 1e-6); bf16 hi/lo out
// ---------------------------------------------------------------------------
__global__ __launch_bounds__(256)
void attn_apply_kernel(const float* __restrict__ QKV, const float* __restrict__ KVf,
                       ushort* __restrict__ O1hi, ushort* __restrict__ O1lo)
{
    const int bh = blockIdx.x;
    const int b = bh >> 4, h = bh & 15;
    const int n0 = blockIdx.y * 16;
    const int t = threadIdx.x;
    const int r  = t >> 4;
    const int e0 = (t & 15) * 4;

    __shared__ float kvs[64][68];
    __shared__ float qs[16][68];
    __shared__ float ksums[64];

    const float* kvb = KVf + (size_t)bh * 4160;
    for (int i = t; i < 4096; i += 256)
        kvs[i >> 6][i & 63] = kvb[i];
    if (t < 64) ksums[t] = kvb[4096 + t];
    {
        const int rr = t >> 4, cc2 = (t & 15) * 4;
        *(float4*)&qs[rr][cc2] =
            *(const float4*)&QKV[(size_t)(b * N_SEQ + n0 + rr) * 3072 + h * 64 + cc2];
    }
    __syncthreads();

    float4 acc = {0.f, 0.f, 0.f, 0.f};
    float accz = 0.f;
    #pragma unroll
    for (int d = 0; d < 64; ++d) {
        const float qv = qs[r][d];
        const float4 kvv = *(const float4*)&kvs[d][e0];
        acc.x += qv * kvv.x; acc.y += qv * kvv.y;
        acc.z += qv * kvv.z; acc.w += qv * kvv.w;
        accz += qv * ksums[d];
    }
    const float Z = 1.f / (accz + 1e-6f);
    const float vv[4] = {acc.x * Z, acc.y * Z, acc.z * Z, acc.w * Z};
    ushort hv[4], lv[4];
    #pragma unroll
    for (int j = 0; j < 4; ++j) {
        hv[j] = f2bf(vv[j]);
        lv[j] = f2bf(vv[j] - bf2f(hv[j]));
    }
    const size_t off = (size_t)(b * N_SEQ + n0 + r) * C_DIM + h * 64 + e0;
    short4v H = {(short)hv[0], (short)hv[1], (short)hv[2], (short)hv[3]};
    short4v L = {(short)lv[0], (short)lv[1], (short)lv[2], (short)lv[3]};
    *(short4v*)&O1hi[off] = H;
    *(short4v*)&O1lo[off] = L;
}

extern "C" void kernel_launch(void* const* d_in, const int* in_sizes, int n_in,
                              void* d_out, int out_size, void* d_ws, size_t ws_size,
                              hipStream_t stream)
{
    const float* x   = (const float*)d_in[0];
    const float* Wq  = (const float*)d_in[1];
    const float* Wkv = (const float*)d_in[2];
    const float* Wo  = (const float*)d_in[3];
    const float* bo  = (const float*)d_in[4];
    float* out = (float*)d_out;

    float* ws   = (float*)d_ws;
    float* QKV  = ws;                                  // 4096*3072 f32
    float* KVp  = QKV + (size_t)M_ROWS * 3072;         // 8*32*4160
    float* KVf  = KVp + (size_t)8 * 32 * 4160;         // 32*4160
    ushort* xhi = (ushort*)(KVf + 32 * 4160);          // 4096*1024 bf16 each
    ushort* xlo = xhi + (size_t)M_ROWS * 1024;         // (O1lo storage)
    ushort* Whi = xlo + (size_t)M_ROWS * 1024;         // 3072*1024 (Wq;Wkv)
    ushort* Wlo = Whi + (size_t)3072 * 1024;           // unused (kept for layout)
    ushort* Wohi = Wlo + (size_t)3072 * 1024;          // 1024*1024
    ushort* Wolo = Wohi + (size_t)1024 * 1024;
    ushort* O1hi = xhi;                                // alias: x dead after GEMM1
    ushort* O1lo = xlo;

    hipFuncSetAttribute((const void*)gemm1_kernel,
                        hipFuncAttributeMaxDynamicSharedMemorySize, 81920);

    // 0. split fp32 -> bf16 (hi-only for x/W; hi+lo for Wo)
    split_all_kernel<<<dim3(4096), 256, 0, stream>>>(
        x, Wq, Wkv, Wo, xhi, Whi, Wohi, Wolo);

    // 1. fused q/k/v projections, single-term bf16, elu1 on q,k
    gemm1_kernel<<<dim3(512), 256, 81920, stream>>>(xhi, Whi, QKV);

    // 2-3. KV = K^T V + ksum (8-way split + deterministic reduce)
    kv_partial_kernel<<<dim3(32, 8), 256, 0, stream>>>(QKV, KVp);
    kv_reduce_kernel<<<dim3((32 * 4160 + 255) / 256), 256, 0, stream>>>(KVp, KVf);

    // 4. O1 = Z * (q @ KV), bf16 hi/lo out
    attn_apply_kernel<<<dim3(32, 128), 256, 0, stream>>>(QKV, KVf, O1hi, O1lo);

    // 5. final projection + bias (3-term)
    gemm2_mfma_kernel<<<dim3(256), 512, 0, stream>>>(O1hi, O1lo, Wohi, Wolo, bo, out);
}

// Round 16
// 112.358 us; speedup vs baseline: 1.3791x; 1.0019x over previous
//
#include <hip/hip_runtime.h>
#include <math.h>

#define C_DIM 1024
#define B_SZ 2
#define N_SEQ 2048
#define M_ROWS (B_SZ * N_SEQ)   // 4096
#define KDIM 1024
#define G1_SLOT 10240           // ushorts per 20KB gemm1 slot (A 8KB + B 12KB)
#define G2_SLOT 8192            // ushorts per 16KB gemm2 slot

typedef float  f32x4   __attribute__((ext_vector_type(4)));
typedef short  bf16x8  __attribute__((ext_vector_type(8)));
typedef short  short4v __attribute__((ext_vector_type(4)));
typedef short  short8v __attribute__((ext_vector_type(8)));

__device__ __forceinline__ float elu1(float v) {
    return v > 0.f ? v + 1.f : expf(v);
}

__device__ __forceinline__ ushort f2bf(float f) {
    union { float f; unsigned u; } x; x.f = f;
    unsigned r = (x.u + 0x7fffu + ((x.u >> 16) & 1u)) >> 16;  // RNE
    return (ushort)r;
}
__device__ __forceinline__ float bf2f(ushort b) {
    union { unsigned u; float f; } x; x.u = ((unsigned)b) << 16;
    return x.f;
}

#define VMCNT(n) asm volatile("s_waitcnt vmcnt(" #n ")" ::: "memory")
// Fence + barrier: all waves' outstanding LDS reads DELIVERED before any wave
// passes the barrier (compiler may sink MFMA lgkm waits past a raw s_barrier
// -> slot-overwrite race, R14 failure).
#define LGKMBAR do {                                                  \
        asm volatile("s_waitcnt lgkmcnt(0)" ::: "memory");            \
        __builtin_amdgcn_sched_barrier(0);                            \
        __builtin_amdgcn_s_barrier();                                 \
    } while (0)

__device__ __forceinline__ void gl16(const ushort* g, ushort* l) {
    __builtin_amdgcn_global_load_lds(
        (const __attribute__((address_space(1))) unsigned int*)g,
        (__attribute__((address_space(3))) unsigned int*)l,
        16, 0, 0);
}

// ---------------------------------------------------------------------------
// fp32 -> bf16 split. x and W(q|kv): hi only. Wo: hi+lo (gemm2 is 3-term).
// ---------------------------------------------------------------------------
__global__ __launch_bounds__(256)
void split_all_kernel(const float* __restrict__ x, const float* __restrict__ Wq,
                      const float* __restrict__ Wkv, const float* __restrict__ Wo,
                      ushort* __restrict__ xhi, ushort* __restrict__ Whi,
                      ushort* __restrict__ Wohi, ushort* __restrict__ Wolo)
{
    const int i = blockIdx.x * 256 + threadIdx.x;   // 0..1048575
    const float* src; ushort* dh; ushort* dl = nullptr; int off;
    if (i < 524288)        { src = x;   dh = xhi;  off = i; }
    else if (i < 655360)   { src = Wq;  dh = Whi;  off = i - 524288; }
    else if (i < 917504)   { src = Wkv; dh = Whi + (1u << 20); off = i - 655360; }
    else                   { src = Wo;  dh = Wohi; dl = Wolo; off = i - 917504; }

    const float4 a = ((const float4*)src)[off * 2];
    const float4 b = ((const float4*)src)[off * 2 + 1];
    const float v[8] = {a.x, a.y, a.z, a.w, b.x, b.y, b.z, b.w};
    ushort hv[8];
    #pragma unroll
    for (int j = 0; j < 8; ++j) hv[j] = f2bf(v[j]);
    short8v H = {(short)hv[0],(short)hv[1],(short)hv[2],(short)hv[3],
                 (short)hv[4],(short)hv[5],(short)hv[6],(short)hv[7]};
    *(short8v*)&dh[(size_t)off * 8] = H;
    if (dl) {
        ushort lv[8];
        #pragma unroll
        for (int j = 0; j < 8; ++j) lv[j] = f2bf(v[j] - bf2f(hv[j]));
        short8v L = {(short)lv[0],(short)lv[1],(short)lv[2],(short)lv[3],
                     (short)lv[4],(short)lv[5],(short)lv[6],(short)lv[7]};
        *(short8v*)&dl[(size_t)off * 8] = L;
    }
}

// ---------------------------------------------------------------------------
// GEMM1: QKV(bf16) = x @ [Wq;Wkv]^T (all 3072 cols), single-term bf16.
// Output stored bf16 (halves write + downstream read traffic; rounding is
// covered by the q-cancellation / k,v-convexity arguments, R13-R15).
// 128x192 tile, BK=32, 4 waves (2x2), wave 64x96. Grid 512 -> 2 blocks/CU
// (80KB). 1 LGKMBAR/kt, 4-slot rotation, depth-3 (vmcnt(10); edges 5/0).
// elu1 on cols<2048; V raw.
// ---------------------------------------------------------------------------
__global__ __launch_bounds__(256, 2)
void gemm1_kernel(const ushort* __restrict__ Ahi, const ushort* __restrict__ Bhi,
                  ushort* __restrict__ dst)
{
    extern __shared__ ushort smem[];   // 4 slots x 10240 ushorts (80 KB)

    const int bid = blockIdx.x;
    const int wg  = (bid & 7) * 64 + (bid >> 3);    // bijective: 512 = 8*64
    const int m0  = (wg >> 4) * 128;                // 32 m-tiles
    const int n0  = (wg & 15) * 192;                // 16 n-tiles

    const int t    = threadIdx.x;
    const int lane = t & 63;
    const int w    = t >> 6;       // 0..3
    const int wr   = w >> 1;       // 0..1  (M half, 64 rows)
    const int wc   = w & 1;        // 0..1  (N half, 96 cols)

    const int gch     = (t & 3) ^ ((t >> 3) & 3);
    const size_t rowA  = (size_t)(m0 + (t >> 2)) * KDIM + gch * 8;   // A rows 0..63
    const size_t rowA2 = rowA + (size_t)64 * KDIM;                   // 64..127
    const size_t rowB  = (size_t)(n0 + (t >> 2)) * KDIM + gch * 8;   // B rows 0..63
    const size_t rowB2 = rowB + (size_t)64 * KDIM;                   // 64..127
    const size_t rowB3 = rowB + (size_t)128 * KDIM;                  // 128..191
    const int wl      = w * 512;

    const int frow = lane & 15;
    const int cc   = (lane >> 4) ^ ((lane >> 1) & 3);
    const int aoff = (wr * 64 + frow) * 32 + cc * 8;
    const int boff = 4096 + (wc * 96 + frow) * 32 + cc * 8;

    f32x4 acc[4][6];
    #pragma unroll
    for (int mi = 0; mi < 4; ++mi)
        #pragma unroll
        for (int nj = 0; nj < 6; ++nj)
            acc[mi][nj] = (f32x4){0.f, 0.f, 0.f, 0.f};

    #define STAGE1(slotp, koff)                                              \
        do {                                                                 \
            ushort* sl_ = (slotp);                                           \
            gl16(Ahi + rowA  + (koff), sl_ + wl);                            \
            gl16(Ahi + rowA2 + (koff), sl_ + 2048 + wl);                     \
            gl16(Bhi + rowB  + (koff), sl_ + 4096 + wl);                     \
            gl16(Bhi + rowB2 + (koff), sl_ + 6144 + wl);                     \
            gl16(Bhi + rowB3 + (koff), sl_ + 8192 + wl);                     \
        } while (0)

    // prologue: kt0->slot0, kt1->slot1, kt2->slot2  (15 loads in flight)
    STAGE1(smem, 0);
    STAGE1(smem + G1_SLOT, 32);
    STAGE1(smem + 2 * G1_SLOT, 64);

    #pragma unroll 1
    for (int kt = 0; kt < 32; ++kt) {
        ushort* sh = smem + (kt & 3) * G1_SLOT;

        if (kt <= 29) { VMCNT(10); } else if (kt == 30) { VMCNT(5); } else { VMCNT(0); }
        LGKMBAR;   // all waves' kt-1 reads DELIVERED before slot reuse
        if (kt <= 28) STAGE1(smem + ((kt + 3) & 3) * G1_SLOT, (kt + 3) * 32);

        bf16x8 ah[4], bh[6];
        #pragma unroll
        for (int mi = 0; mi < 4; ++mi)
            ah[mi] = *(const bf16x8*)(sh + aoff + mi * 512);
        #pragma unroll
        for (int nj = 0; nj < 6; ++nj)
            bh[nj] = *(const bf16x8*)(sh + boff + nj * 512);
        __builtin_amdgcn_s_setprio(1);
        #pragma unroll
        for (int mi = 0; mi < 4; ++mi)
            #pragma unroll
            for (int nj = 0; nj < 6; ++nj)
                acc[mi][nj] = __builtin_amdgcn_mfma_f32_16x16x32_bf16(
                    ah[mi], bh[nj], acc[mi][nj], 0, 0, 0);
        __builtin_amdgcn_s_setprio(0);
    }
    #undef STAGE1

    const int erow  = m0 + wr * 64 + (lane >> 4) * 4;
    const int ecol0 = n0 + wc * 96 + frow;
    #pragma unroll
    for (int mi = 0; mi < 4; ++mi) {
        #pragma unroll
        for (int j = 0; j < 4; ++j) {
            const int row = erow + mi * 16 + j;
            #pragma unroll
            for (int nj = 0; nj < 6; ++nj) {
                const int col = ecol0 + nj * 16;
                float v = acc[mi][nj][j];
                if (col < 2048) v = elu1(v);   // Q,K get elu1; V raw
                dst[(size_t)row * 3072 + col] = f2bf(v);
            }
        }
    }
}

// ---------------------------------------------------------------------------
// GEMM2: out = O1 @ Wo^T + bo. 3-term split-bf16. 128x128 tile, BK=32,
// 8 waves (2M x 4N), wave tile 64x32. Grid 256 full fill. 3-phase depth-3
// (vmcnt(4)/2/0), LGKMBAR-fenced barriers. 64KB LDS.
// ---------------------------------------------------------------------------
__global__ __launch_bounds__(512, 2)
void gemm2_mfma_kernel(const ushort* __restrict__ Ahi, const ushort* __restrict__ Alo,
                       const ushort* __restrict__ Bhi, const ushort* __restrict__ Blo,
                       const float* __restrict__ bias, float* __restrict__ dst)
{
    __shared__ ushort smem[4 * G2_SLOT];   // 64 KB

    const int bid = blockIdx.x;
    const int wg  = (bid & 7) * 32 + (bid >> 3);    // bijective: 256 = 8*32
    const int m0  = (wg >> 3) * 128;
    const int n0  = (wg & 7) * 128;

    const int t    = threadIdx.x;
    const int lane = t & 63;
    const int w    = t >> 6;      // 0..7
    const int wr   = w >> 2;      // 0..1
    const int wc   = w & 3;       // 0..3

    const int gch     = (t & 3) ^ ((t >> 3) & 3);
    const size_t rowA = (size_t)(m0 + (t >> 2)) * KDIM + gch * 8;
    const size_t rowB = (size_t)(n0 + (t >> 2)) * KDIM + gch * 8;
    const int wl      = w * 512;

    const int frow = lane & 15;
    const int cc   = (lane >> 4) ^ ((lane >> 1) & 3);
    const int aoff = (wr * 64 + frow) * 32 + cc * 8;
    const int boff = 4096 + (wc * 32 + frow) * 32 + cc * 8;

    f32x4 acc[4][2];
    #pragma unroll
    for (int mi = 0; mi < 4; ++mi)
        #pragma unroll
        for (int nj = 0; nj < 2; ++nj)
            acc[mi][nj] = (f32x4){0.f, 0.f, 0.f, 0.f};

    #define STAGE2(srcA, srcB, slotp, koff)                                  \
        do {                                                                 \
            ushort* p_ = (slotp);                                            \
            gl16((srcA) + rowA + (koff), p_ + wl);                           \
            gl16((srcB) + rowB + (koff), p_ + 4096 + wl);                    \
        } while (0)

    STAGE2(Ahi, Bhi, smem, 0);
    STAGE2(Alo, Blo, smem + G2_SLOT, 0);
    STAGE2(Ahi, Bhi, smem + 2 * G2_SLOT, 32);

    #pragma unroll 1
    for (int kt = 0; kt < 32; ++kt) {
        ushort* sh = smem + ((2 * kt) & 3) * G2_SLOT;
        ushort* sl = smem + ((2 * kt + 1) & 3) * G2_SLOT;
        ushort* nl = smem + ((2 * kt + 3) & 3) * G2_SLOT;
        const int kn1 = (kt + 1) * 32;
        const int kn2 = (kt + 2) * 32;

        bf16x8 ah[4], bh[2], bl[2], al[4];

        // ---- ph1: hh
        if (kt < 31) { VMCNT(4); } else { VMCNT(2); }
        LGKMBAR;
        if (kt < 31) STAGE2(Alo, Blo, nl, kn1);
        #pragma unroll
        for (int mi = 0; mi < 4; ++mi)
            ah[mi] = *(const bf16x8*)(sh + aoff + mi * 512);
        #pragma unroll
        for (int nj = 0; nj < 2; ++nj)
            bh[nj] = *(const bf16x8*)(sh + boff + nj * 512);
        __builtin_amdgcn_s_setprio(1);
        #pragma unroll
        for (int mi = 0; mi < 4; ++mi)
            #pragma unroll
            for (int nj = 0; nj < 2; ++nj)
                acc[mi][nj] = __builtin_amdgcn_mfma_f32_16x16x32_bf16(
                    ah[mi], bh[nj], acc[mi][nj], 0, 0, 0);
        __builtin_amdgcn_s_setprio(0);

        // ---- ph2: hl
        if (kt < 31) { VMCNT(4); } else { VMCNT(0); }
        LGKMBAR;
        if (kt < 30) STAGE2(Ahi, Bhi, sh, kn2);
        #pragma unroll
        for (int nj = 0; nj < 2; ++nj)
            bl[nj] = *(const bf16x8*)(sl + boff + nj * 512);
        #pragma unroll
        for (int mi = 0; mi < 4; ++mi)
            al[mi] = *(const bf16x8*)(sl + aoff + mi * 512);
        __builtin_amdgcn_s_setprio(1);
        #pragma unroll
        for (int mi = 0; mi < 4; ++mi)
            #pragma unroll
            for (int nj = 0; nj < 2; ++nj)
                acc[mi][nj] = __builtin_amdgcn_mfma_f32_16x16x32_bf16(
                    ah[mi], bl[nj], acc[mi][nj], 0, 0, 0);
        __builtin_amdgcn_s_setprio(0);

        // ---- ph3: lh (register-only)
        __builtin_amdgcn_s_setprio(1);
        #pragma unroll
        for (int mi = 0; mi < 4; ++mi)
            #pragma unroll
            for (int nj = 0; nj < 2; ++nj)
                acc[mi][nj] = __builtin_amdgcn_mfma_f32_16x16x32_bf16(
                    al[mi], bh[nj], acc[mi][nj], 0, 0, 0);
        __builtin_amdgcn_s_setprio(0);
    }
    #undef STAGE2

    const int erow  = m0 + wr * 64 + (lane >> 4) * 4;
    const int ecol0 = n0 + wc * 32 + frow;
    #pragma unroll
    for (int mi = 0; mi < 4; ++mi) {
        #pragma unroll
        for (int j = 0; j < 4; ++j) {
            const int row = erow + mi * 16 + j;
            #pragma unroll
            for (int nj = 0; nj < 2; ++nj) {
                const int col = ecol0 + nj * 16;
                dst[(size_t)row * 1024 + col] = acc[mi][nj][j] + bias[col];
            }
        }
    }
}

// ---------------------------------------------------------------------------
// Partial KV = K_feat^T V and ksum, per (b,h), 8-way N split (256 rows each).
// QKV now bf16: stage short4v, convert to f32 in LDS; compute unchanged.
// ---------------------------------------------------------------------------
__global__ __launch_bounds__(256)
void kv_partial_kernel(const ushort* __restrict__ QKV, float* __restrict__ KVp)
{
    const int bh = blockIdx.x;   // 0..31
    const int s  = blockIdx.y;   // 0..7
    const int b  = bh >> 4;
    const int h  = bh & 15;
    const int t  = threadIdx.x;

    __shared__ float ks[16][64];
    __shared__ float vs[16][64];
    __shared__ float red[4160];

    const int srow = t >> 4;
    const int scol = (t & 15) * 4;
    const size_t gk = (size_t)(b * N_SEQ + s * 256) * 3072 + 1024 + h * 64 + scol;
    const size_t gv = gk + 1024;

    const int rs = t >> 6;
    const int dg = (t >> 3) & 7;
    const int eg = t & 7;
    const int d0 = dg * 8;
    const int e0 = eg * 8;

    float acc[8][8];
    #pragma unroll
    for (int i = 0; i < 8; ++i)
        #pragma unroll
        for (int j = 0; j < 8; ++j) acc[i][j] = 0.f;
    float aks[8] = {0.f, 0.f, 0.f, 0.f, 0.f, 0.f, 0.f, 0.f};

    short4v kr = *(const short4v*)&QKV[gk + (size_t)srow * 3072];
    short4v vr = *(const short4v*)&QKV[gv + (size_t)srow * 3072];

    for (int it = 0; it < 16; ++it) {
        __syncthreads();
        ks[srow][scol + 0] = bf2f((ushort)kr[0]);
        ks[srow][scol + 1] = bf2f((ushort)kr[1]);
        ks[srow][scol + 2] = bf2f((ushort)kr[2]);
        ks[srow][scol + 3] = bf2f((ushort)kr[3]);
        vs[srow][scol + 0] = bf2f((ushort)vr[0]);
        vs[srow][scol + 1] = bf2f((ushort)vr[1]);
        vs[srow][scol + 2] = bf2f((ushort)vr[2]);
        vs[srow][scol + 3] = bf2f((ushort)vr[3]);
        __syncthreads();
        if (it < 15) {
            kr = *(const short4v*)&QKV[gk + (size_t)((it + 1) * 16 + srow) * 3072];
            vr = *(const short4v*)&QKV[gv + (size_t)((it + 1) * 16 + srow) * 3072];
        }
        #pragma unroll
        for (int rr = 0; rr < 4; ++rr) {
            const int r = rs * 4 + rr;
            const float4 ka = *(const float4*)&ks[r][d0];
            const float4 kb = *(const float4*)&ks[r][d0 + 4];
            const float4 va = *(const float4*)&vs[r][e0];
            const float4 vb = *(const float4*)&vs[r][e0 + 4];
            const float k8[8] = {ka.x, ka.y, ka.z, ka.w, kb.x, kb.y, kb.z, kb.w};
            const float v8[8] = {va.x, va.y, va.z, va.w, vb.x, vb.y, vb.z, vb.w};
            #pragma unroll
            for (int i = 0; i < 8; ++i)
                #pragma unroll
                for (int j = 0; j < 8; ++j)
                    acc[i][j] += k8[i] * v8[j];
            if (eg == 0) {
                #pragma unroll
                for (int i = 0; i < 8; ++i) aks[i] += k8[i];
            }
        }
    }

    #pragma unroll 1
    for (int step = 1; step < 4; ++step) {
        __syncthreads();
        if (rs == step) {
            #pragma unroll
            for (int i = 0; i < 8; ++i)
                #pragma unroll
                for (int j = 0; j < 8; ++j)
                    red[(d0 + i) * 64 + e0 + j] = acc[i][j];
            if (eg == 0) {
                #pragma unroll
                for (int i = 0; i < 8; ++i) red[4096 + d0 + i] = aks[i];
            }
        }
        __syncthreads();
        if (rs == 0) {
            #pragma unroll
            for (int i = 0; i < 8; ++i)
                #pragma unroll
                for (int j = 0; j < 8; ++j)
                    acc[i][j] += red[(d0 + i) * 64 + e0 + j];
            if (eg == 0) {
                #pragma unroll
                for (int i = 0; i < 8; ++i) aks[i] += red[4096 + d0 + i];
            }
        }
    }

    if (rs == 0) {
        float* outp = KVp + ((size_t)s * 32 + bh) * 4160;
        #pragma unroll
        for (int i = 0; i < 8; ++i) {
            float4 o0 = {acc[i][0], acc[i][1], acc[i][2], acc[i][3]};
            float4 o1 = {acc[i][4], acc[i][5], acc[i][6], acc[i][7]};
            *(float4*)(outp + (d0 + i) * 64 + e0)     = o0;
            *(float4*)(outp + (d0 + i) * 64 + e0 + 4) = o1;
        }
        if (eg == 0) {
            #pragma unroll
            for (int i = 0; i < 8; ++i) outp[4096 + d0 + i] = aks[i];
        }
    }
}

__global__ __launch_bounds__(256)
void kv_reduce_kernel(const float* __restrict__ KVp, float* __restrict__ KVf)
{
    const int idx = blockIdx.x * 256 + threadIdx.x;
    if (idx < 32 * 4160) {
        float s = 0.f;
        #pragma unroll
        for (int i = 0; i < 8; ++i) s += KVp[(size_t)i * (32 * 4160) + idx];
        KVf[idx] = s;
    }
}

// ---------------------------------------------------------------------------
// O1[n, h*64+e] = Z * sum_d q[n,d]*KV[d,e], Z = 1/(q.ksum + 1e-6).
// Q read bf16; O1 emitted bf16 hi/lo for the 3-term gemm2.
// ---------------------------------------------------------------------------
__global__ __launch_bounds__(256)
void attn_apply_kernel(const ushort* __restrict__ QKV, const float* __restrict__ KVf,
                       ushort* __restrict__ O1hi, ushort* __restrict__ O1lo)
{
    const int bh = blockIdx.x;
    const int b = bh >> 4, h = bh & 15;
    const int n0 = blockIdx.y * 16;
    const int t = threadIdx.x;
    const int r  = t >> 4;
    const int e0 = (t & 15) * 4;

    __shared__ float kvs[64][68];
    __shared__ float qs[16][68];
    __shared__ float ksums[64];

    const float* kvb = KVf + (size_t)bh * 4160;
    for (int i = t; i < 4096; i += 256)
        kvs[i >> 6][i & 63] = kvb[i];
    if (t < 64) ksums[t] = kvb[4096 + t];
    {
        const int rr = t >> 4, cc2 = (t & 15) * 4;
        short4v q4 = *(const short4v*)&QKV[(size_t)(b * N_SEQ + n0 + rr) * 3072 + h * 64 + cc2];
        qs[rr][cc2 + 0] = bf2f((ushort)q4[0]);
        qs[rr][cc2 + 1] = bf2f((ushort)q4[1]);
        qs[rr][cc2 + 2] = bf2f((ushort)q4[2]);
        qs[rr][cc2 + 3] = bf2f((ushort)q4[3]);
    }
    __syncthreads();

    float4 acc = {0.f, 0.f, 0.f, 0.f};
    float accz = 0.f;
    #pragma unroll
    for (int d = 0; d < 64; ++d) {
        const float qv = qs[r][d];
        const float4 kvv = *(const float4*)&kvs[d][e0];
        acc.x += qv * kvv.x; acc.y += qv * kvv.y;
        acc.z += qv * kvv.z; acc.w += qv * kvv.w;
        accz += qv * ksums[d];
    }
    const float Z = 1.f / (accz + 1e-6f);
    const float vv[4] = {acc.x * Z, acc.y * Z, acc.z * Z, acc.w * Z};
    ushort hv[4], lv[4];
    #pragma unroll
    for (int j = 0; j < 4; ++j) {
        hv[j] = f2bf(vv[j]);
        lv[j] = f2bf(vv[j] - bf2f(hv[j]));
    }
    const size_t off = (size_t)(b * N_SEQ + n0 + r) * C_DIM + h * 64 + e0;
    short4v H = {(short)hv[0], (short)hv[1], (short)hv[2], (short)hv[3]};
    short4v L = {(short)lv[0], (short)lv[1], (short)lv[2], (short)lv[3]};
    *(short4v*)&O1hi[off] = H;
    *(short4v*)&O1lo[off] = L;
}

extern "C" void kernel_launch(void* const* d_in, const int* in_sizes, int n_in,
                              void* d_out, int out_size, void* d_ws, size_t ws_size,
                              hipStream_t stream)
{
    const float* x   = (const float*)d_in[0];
    const float* Wq  = (const float*)d_in[1];
    const float* Wkv = (const float*)d_in[2];
    const float* Wo  = (const float*)d_in[3];
    const float* bo  = (const float*)d_in[4];
    float* out = (float*)d_out;

    float* ws    = (float*)d_ws;
    ushort* QKVu = (ushort*)ws;                        // 4096*3072 bf16 (24 MB)
    float* KVp   = ws + (size_t)M_ROWS * 3072 / 2;     // 8*32*4160 f32
    float* KVf   = KVp + (size_t)8 * 32 * 4160;        // 32*4160
    ushort* xhi  = (ushort*)(KVf + 32 * 4160);         // 4096*1024 bf16 each
    ushort* xlo  = xhi + (size_t)M_ROWS * 1024;        // (O1lo storage)
    ushort* Whi  = xlo + (size_t)M_ROWS * 1024;        // 3072*1024 (Wq;Wkv)
    ushort* Wlo  = Whi + (size_t)3072 * 1024;          // unused (layout keep)
    ushort* Wohi = Wlo + (size_t)3072 * 1024;          // 1024*1024
    ushort* Wolo = Wohi + (size_t)1024 * 1024;
    ushort* O1hi = xhi;                                // alias: x dead after GEMM1
    ushort* O1lo = xlo;

    hipFuncSetAttribute((const void*)gemm1_kernel,
                        hipFuncAttributeMaxDynamicSharedMemorySize, 81920);

    // 0. split fp32 -> bf16 (hi-only for x/W; hi+lo for Wo)
    split_all_kernel<<<dim3(4096), 256, 0, stream>>>(
        x, Wq, Wkv, Wo, xhi, Whi, Wohi, Wolo);

    // 1. fused q/k/v projections, single-term bf16, bf16 output
    gemm1_kernel<<<dim3(512), 256, 81920, stream>>>(xhi, Whi, QKVu);

    // 2-3. KV = K^T V + ksum (8-way split + deterministic reduce)
    kv_partial_kernel<<<dim3(32, 8), 256, 0, stream>>>(QKVu, KVp);
    kv_reduce_kernel<<<dim3((32 * 4160 + 255) / 256), 256, 0, stream>>>(KVp, KVf);

    // 4. O1 = Z * (q @ KV), bf16 hi/lo out
    attn_apply_kernel<<<dim3(32, 128), 256, 0, stream>>>(QKVu, KVf, O1hi, O1lo);

    // 5. final projection + bias (3-term)
    gemm2_mfma_kernel<<<dim3(256), 512, 0, stream>>>(O1hi, O1lo, Wohi, Wolo, bo, out);
}

// Round 17
// 99.658 us; speedup vs baseline: 1.5549x; 1.1274x over previous
//
#include <hip/hip_runtime.h>
#include <math.h>

#define C_DIM 1024
#define B_SZ 2
#define N_SEQ 2048
#define M_ROWS (B_SZ * N_SEQ)   // 4096
#define KDIM 1024
#define G1_SLOT 10240           // ushorts per 20KB gemm1 slot (A 8KB + B 12KB)
#define G2_SLOT 6144            // ushorts per 12KB gemm2 slot (A 4KB + B 8KB)

typedef float  f32x4   __attribute__((ext_vector_type(4)));
typedef short  bf16x8  __attribute__((ext_vector_type(8)));
typedef short  short4v __attribute__((ext_vector_type(4)));
typedef short  short8v __attribute__((ext_vector_type(8)));

__device__ __forceinline__ float elu1(float v) {
    return v > 0.f ? v + 1.f : expf(v);
}

__device__ __forceinline__ ushort f2bf(float f) {
    union { float f; unsigned u; } x; x.f = f;
    unsigned r = (x.u + 0x7fffu + ((x.u >> 16) & 1u)) >> 16;  // RNE
    return (ushort)r;
}
__device__ __forceinline__ float bf2f(ushort b) {
    union { unsigned u; float f; } x; x.u = ((unsigned)b) << 16;
    return x.f;
}

#define VMCNT(n) asm volatile("s_waitcnt vmcnt(" #n ")" ::: "memory")
// Fence + barrier: all waves' outstanding LDS reads DELIVERED before any wave
// passes the barrier (compiler may sink MFMA lgkm waits past a raw s_barrier
// -> slot-overwrite race, R14 failure).
#define LGKMBAR do {                                                  \
        asm volatile("s_waitcnt lgkmcnt(0)" ::: "memory");            \
        __builtin_amdgcn_sched_barrier(0);                            \
        __builtin_amdgcn_s_barrier();                                 \
    } while (0)

__device__ __forceinline__ void gl16(const ushort* g, ushort* l) {
    __builtin_amdgcn_global_load_lds(
        (const __attribute__((address_space(1))) unsigned int*)g,
        (__attribute__((address_space(3))) unsigned int*)l,
        16, 0, 0);
}

// ---------------------------------------------------------------------------
// fp32 -> bf16 (hi only, RNE) for x, [Wq;Wkv], Wo. 8 elems/thread.
// ---------------------------------------------------------------------------
__global__ __launch_bounds__(256)
void split_all_kernel(const float* __restrict__ x, const float* __restrict__ Wq,
                      const float* __restrict__ Wkv, const float* __restrict__ Wo,
                      ushort* __restrict__ xhi, ushort* __restrict__ Whi,
                      ushort* __restrict__ Wohi)
{
    const int i = blockIdx.x * 256 + threadIdx.x;   // 0..1048575
    const float* src; ushort* dh; int off;
    if (i < 524288)        { src = x;   dh = xhi;  off = i; }
    else if (i < 655360)   { src = Wq;  dh = Whi;  off = i - 524288; }
    else if (i < 917504)   { src = Wkv; dh = Whi + (1u << 20); off = i - 655360; }
    else                   { src = Wo;  dh = Wohi; off = i - 917504; }

    const float4 a = ((const float4*)src)[off * 2];
    const float4 b = ((const float4*)src)[off * 2 + 1];
    const float v[8] = {a.x, a.y, a.z, a.w, b.x, b.y, b.z, b.w};
    ushort hv[8];
    #pragma unroll
    for (int j = 0; j < 8; ++j) hv[j] = f2bf(v[j]);
    short8v H = {(short)hv[0],(short)hv[1],(short)hv[2],(short)hv[3],
                 (short)hv[4],(short)hv[5],(short)hv[6],(short)hv[7]};
    *(short8v*)&dh[(size_t)off * 8] = H;
}

// ---------------------------------------------------------------------------
// GEMM1: QKV(bf16) = x @ [Wq;Wkv]^T (3072 cols), single-term bf16.
// 128x192 tile, BK=32, 4 waves (2x2), wave 64x96. Grid 512 -> 2 blocks/CU
// (80KB). 1 LGKMBAR/kt, 4-slot rotation, depth-3 (vmcnt(10); edges 5/0).
// elu1 on cols<2048; V raw.
// ---------------------------------------------------------------------------
__global__ __launch_bounds__(256, 2)
void gemm1_kernel(const ushort* __restrict__ Ahi, const ushort* __restrict__ Bhi,
                  ushort* __restrict__ dst)
{
    extern __shared__ ushort smem[];   // 4 slots x 10240 ushorts (80 KB)

    const int bid = blockIdx.x;
    const int wg  = (bid & 7) * 64 + (bid >> 3);    // bijective: 512 = 8*64
    const int m0  = (wg >> 4) * 128;                // 32 m-tiles
    const int n0  = (wg & 15) * 192;                // 16 n-tiles

    const int t    = threadIdx.x;
    const int lane = t & 63;
    const int w    = t >> 6;       // 0..3
    const int wr   = w >> 1;       // 0..1  (M half, 64 rows)
    const int wc   = w & 1;        // 0..1  (N half, 96 cols)

    const int gch     = (t & 3) ^ ((t >> 3) & 3);
    const size_t rowA  = (size_t)(m0 + (t >> 2)) * KDIM + gch * 8;   // A rows 0..63
    const size_t rowA2 = rowA + (size_t)64 * KDIM;                   // 64..127
    const size_t rowB  = (size_t)(n0 + (t >> 2)) * KDIM + gch * 8;   // B rows 0..63
    const size_t rowB2 = rowB + (size_t)64 * KDIM;                   // 64..127
    const size_t rowB3 = rowB + (size_t)128 * KDIM;                  // 128..191
    const int wl      = w * 512;

    const int frow = lane & 15;
    const int cc   = (lane >> 4) ^ ((lane >> 1) & 3);
    const int aoff = (wr * 64 + frow) * 32 + cc * 8;
    const int boff = 4096 + (wc * 96 + frow) * 32 + cc * 8;

    f32x4 acc[4][6];
    #pragma unroll
    for (int mi = 0; mi < 4; ++mi)
        #pragma unroll
        for (int nj = 0; nj < 6; ++nj)
            acc[mi][nj] = (f32x4){0.f, 0.f, 0.f, 0.f};

    #define STAGE1(slotp, koff)                                              \
        do {                                                                 \
            ushort* sl_ = (slotp);                                           \
            gl16(Ahi + rowA  + (koff), sl_ + wl);                            \
            gl16(Ahi + rowA2 + (koff), sl_ + 2048 + wl);                     \
            gl16(Bhi + rowB  + (koff), sl_ + 4096 + wl);                     \
            gl16(Bhi + rowB2 + (koff), sl_ + 6144 + wl);                     \
            gl16(Bhi + rowB3 + (koff), sl_ + 8192 + wl);                     \
        } while (0)

    // prologue: kt0->slot0, kt1->slot1, kt2->slot2  (15 loads in flight)
    STAGE1(smem, 0);
    STAGE1(smem + G1_SLOT, 32);
    STAGE1(smem + 2 * G1_SLOT, 64);

    #pragma unroll 1
    for (int kt = 0; kt < 32; ++kt) {
        ushort* sh = smem + (kt & 3) * G1_SLOT;

        if (kt <= 29) { VMCNT(10); } else if (kt == 30) { VMCNT(5); } else { VMCNT(0); }
        LGKMBAR;   // all waves' kt-1 reads DELIVERED before slot reuse
        if (kt <= 28) STAGE1(smem + ((kt + 3) & 3) * G1_SLOT, (kt + 3) * 32);

        bf16x8 ah[4], bh[6];
        #pragma unroll
        for (int mi = 0; mi < 4; ++mi)
            ah[mi] = *(const bf16x8*)(sh + aoff + mi * 512);
        #pragma unroll
        for (int nj = 0; nj < 6; ++nj)
            bh[nj] = *(const bf16x8*)(sh + boff + nj * 512);
        __builtin_amdgcn_s_setprio(1);
        #pragma unroll
        for (int mi = 0; mi < 4; ++mi)
            #pragma unroll
            for (int nj = 0; nj < 6; ++nj)
                acc[mi][nj] = __builtin_amdgcn_mfma_f32_16x16x32_bf16(
                    ah[mi], bh[nj], acc[mi][nj], 0, 0, 0);
        __builtin_amdgcn_s_setprio(0);
    }
    #undef STAGE1

    const int erow  = m0 + wr * 64 + (lane >> 4) * 4;
    const int ecol0 = n0 + wc * 96 + frow;
    #pragma unroll
    for (int mi = 0; mi < 4; ++mi) {
        #pragma unroll
        for (int j = 0; j < 4; ++j) {
            const int row = erow + mi * 16 + j;
            #pragma unroll
            for (int nj = 0; nj < 6; ++nj) {
                const int col = ecol0 + nj * 16;
                float v = acc[mi][nj][j];
                if (col < 2048) v = elu1(v);   // Q,K get elu1; V raw
                dst[(size_t)row * 3072 + col] = f2bf(v);
            }
        }
    }
}

// ---------------------------------------------------------------------------
// GEMM2: out = O1 @ Wo^T + bo, SINGLE-TERM bf16 (error budget analysis:
// +~8e-4 incoherent on top of the 4.9e-4 floor, under the 1.92e-3 threshold).
// 64x128 tile, BK=32, 4 waves (1M x 4N), wave tile 64x32. Grid 512 =
// 64m x 8n -> 2 blocks/CU (48KB). 1 LGKMBAR/kt, 4-slot rotation, depth-3
// (3-load units, vmcnt(6); edges 3/0).
// ---------------------------------------------------------------------------
__global__ __launch_bounds__(256, 2)
void gemm2_kernel(const ushort* __restrict__ O1, const ushort* __restrict__ Wo,
                  const float* __restrict__ bias, float* __restrict__ dst)
{
    __shared__ ushort smem[4 * G2_SLOT];   // 48 KB

    const int bid = blockIdx.x;
    const int wg  = (bid & 7) * 64 + (bid >> 3);    // bijective: 512 = 8*64
    const int m0  = (wg >> 3) * 64;                 // 64 m-tiles
    const int n0  = (wg & 7) * 128;                 // 8 n-tiles

    const int t    = threadIdx.x;
    const int lane = t & 63;
    const int w    = t >> 6;      // 0..3 (N quarters, 32 cols)

    const int gch     = (t & 3) ^ ((t >> 3) & 3);
    const size_t rowA  = (size_t)(m0 + (t >> 2)) * KDIM + gch * 8;   // 64 rows
    const size_t rowB  = (size_t)(n0 + (t >> 2)) * KDIM + gch * 8;   // rows 0..63
    const size_t rowB2 = rowB + (size_t)64 * KDIM;                   // 64..127
    const int wl      = w * 512;

    const int frow = lane & 15;
    const int cc   = (lane >> 4) ^ ((lane >> 1) & 3);
    const int aoff = frow * 32 + cc * 8;
    const int boff = 2048 + (w * 32 + frow) * 32 + cc * 8;

    f32x4 acc[4][2];
    #pragma unroll
    for (int mi = 0; mi < 4; ++mi)
        #pragma unroll
        for (int nj = 0; nj < 2; ++nj)
            acc[mi][nj] = (f32x4){0.f, 0.f, 0.f, 0.f};

    #define STAGE2(slotp, koff)                                              \
        do {                                                                 \
            ushort* p_ = (slotp);                                            \
            gl16(O1 + rowA  + (koff), p_ + wl);                              \
            gl16(Wo + rowB  + (koff), p_ + 2048 + wl);                       \
            gl16(Wo + rowB2 + (koff), p_ + 4096 + wl);                       \
        } while (0)

    // prologue: kt0->slot0, kt1->slot1, kt2->slot2  (9 loads in flight)
    STAGE2(smem, 0);
    STAGE2(smem + G2_SLOT, 32);
    STAGE2(smem + 2 * G2_SLOT, 64);

    #pragma unroll 1
    for (int kt = 0; kt < 32; ++kt) {
        ushort* sh = smem + (kt & 3) * G2_SLOT;

        if (kt <= 29) { VMCNT(6); } else if (kt == 30) { VMCNT(3); } else { VMCNT(0); }
        LGKMBAR;
        if (kt <= 28) STAGE2(smem + ((kt + 3) & 3) * G2_SLOT, (kt + 3) * 32);

        bf16x8 ah[4], bh[2];
        #pragma unroll
        for (int mi = 0; mi < 4; ++mi)
            ah[mi] = *(const bf16x8*)(sh + aoff + mi * 512);
        #pragma unroll
        for (int nj = 0; nj < 2; ++nj)
            bh[nj] = *(const bf16x8*)(sh + boff + nj * 512);
        __builtin_amdgcn_s_setprio(1);
        #pragma unroll
        for (int mi = 0; mi < 4; ++mi)
            #pragma unroll
            for (int nj = 0; nj < 2; ++nj)
                acc[mi][nj] = __builtin_amdgcn_mfma_f32_16x16x32_bf16(
                    ah[mi], bh[nj], acc[mi][nj], 0, 0, 0);
        __builtin_amdgcn_s_setprio(0);
    }
    #undef STAGE2

    const int erow  = m0 + (lane >> 4) * 4;
    const int ecol0 = n0 + w * 32 + frow;
    #pragma unroll
    for (int mi = 0; mi < 4; ++mi) {
        #pragma unroll
        for (int j = 0; j < 4; ++j) {
            const int row = erow + mi * 16 + j;
            #pragma unroll
            for (int nj = 0; nj < 2; ++nj) {
                const int col = ecol0 + nj * 16;
                dst[(size_t)row * 1024 + col] = acc[mi][nj][j] + bias[col];
            }
        }
    }
}

// ---------------------------------------------------------------------------
// Partial KV = K_feat^T V and ksum, per (b,h), 8-way N split (256 rows each).
// QKV bf16: stage short4v, convert to f32 in LDS; compute f32.
// ---------------------------------------------------------------------------
__global__ __launch_bounds__(256)
void kv_partial_kernel(const ushort* __restrict__ QKV, float* __restrict__ KVp)
{
    const int bh = blockIdx.x;   // 0..31
    const int s  = blockIdx.y;   // 0..7
    const int b  = bh >> 4;
    const int h  = bh & 15;
    const int t  = threadIdx.x;

    __shared__ float ks[16][64];
    __shared__ float vs[16][64];
    __shared__ float red[4160];

    const int srow = t >> 4;
    const int scol = (t & 15) * 4;
    const size_t gk = (size_t)(b * N_SEQ + s * 256) * 3072 + 1024 + h * 64 + scol;
    const size_t gv = gk + 1024;

    const int rs = t >> 6;
    const int dg = (t >> 3) & 7;
    const int eg = t & 7;
    const int d0 = dg * 8;
    const int e0 = eg * 8;

    float acc[8][8];
    #pragma unroll
    for (int i = 0; i < 8; ++i)
        #pragma unroll
        for (int j = 0; j < 8; ++j) acc[i][j] = 0.f;
    float aks[8] = {0.f, 0.f, 0.f, 0.f, 0.f, 0.f, 0.f, 0.f};

    short4v kr = *(const short4v*)&QKV[gk + (size_t)srow * 3072];
    short4v vr = *(const short4v*)&QKV[gv + (size_t)srow * 3072];

    for (int it = 0; it < 16; ++it) {
        __syncthreads();
        ks[srow][scol + 0] = bf2f((ushort)kr[0]);
        ks[srow][scol + 1] = bf2f((ushort)kr[1]);
        ks[srow][scol + 2] = bf2f((ushort)kr[2]);
        ks[srow][scol + 3] = bf2f((ushort)kr[3]);
        vs[srow][scol + 0] = bf2f((ushort)vr[0]);
        vs[srow][scol + 1] = bf2f((ushort)vr[1]);
        vs[srow][scol + 2] = bf2f((ushort)vr[2]);
        vs[srow][scol + 3] = bf2f((ushort)vr[3]);
        __syncthreads();
        if (it < 15) {
            kr = *(const short4v*)&QKV[gk + (size_t)((it + 1) * 16 + srow) * 3072];
            vr = *(const short4v*)&QKV[gv + (size_t)((it + 1) * 16 + srow) * 3072];
        }
        #pragma unroll
        for (int rr = 0; rr < 4; ++rr) {
            const int r = rs * 4 + rr;
            const float4 ka = *(const float4*)&ks[r][d0];
            const float4 kb = *(const float4*)&ks[r][d0 + 4];
            const float4 va = *(const float4*)&vs[r][e0];
            const float4 vb = *(const float4*)&vs[r][e0 + 4];
            const float k8[8] = {ka.x, ka.y, ka.z, ka.w, kb.x, kb.y, kb.z, kb.w};
            const float v8[8] = {va.x, va.y, va.z, va.w, vb.x, vb.y, vb.z, vb.w};
            #pragma unroll
            for (int i = 0; i < 8; ++i)
                #pragma unroll
                for (int j = 0; j < 8; ++j)
                    acc[i][j] += k8[i] * v8[j];
            if (eg == 0) {
                #pragma unroll
                for (int i = 0; i < 8; ++i) aks[i] += k8[i];
            }
        }
    }

    #pragma unroll 1
    for (int step = 1; step < 4; ++step) {
        __syncthreads();
        if (rs == step) {
            #pragma unroll
            for (int i = 0; i < 8; ++i)
                #pragma unroll
                for (int j = 0; j < 8; ++j)
                    red[(d0 + i) * 64 + e0 + j] = acc[i][j];
            if (eg == 0) {
                #pragma unroll
                for (int i = 0; i < 8; ++i) red[4096 + d0 + i] = aks[i];
            }
        }
        __syncthreads();
        if (rs == 0) {
            #pragma unroll
            for (int i = 0; i < 8; ++i)
                #pragma unroll
                for (int j = 0; j < 8; ++j)
                    acc[i][j] += red[(d0 + i) * 64 + e0 + j];
            if (eg == 0) {
                #pragma unroll
                for (int i = 0; i < 8; ++i) aks[i] += red[4096 + d0 + i];
            }
        }
    }

    if (rs == 0) {
        float* outp = KVp + ((size_t)s * 32 + bh) * 4160;
        #pragma unroll
        for (int i = 0; i < 8; ++i) {
            float4 o0 = {acc[i][0], acc[i][1], acc[i][2], acc[i][3]};
            float4 o1 = {acc[i][4], acc[i][5], acc[i][6], acc[i][7]};
            *(float4*)(outp + (d0 + i) * 64 + e0)     = o0;
            *(float4*)(outp + (d0 + i) * 64 + e0 + 4) = o1;
        }
        if (eg == 0) {
            #pragma unroll
            for (int i = 0; i < 8; ++i) outp[4096 + d0 + i] = aks[i];
        }
    }
}

__global__ __launch_bounds__(256)
void kv_reduce_kernel(const float* __restrict__ KVp, float* __restrict__ KVf)
{
    const int idx = blockIdx.x * 256 + threadIdx.x;
    if (idx < 32 * 4160) {
        float s = 0.f;
        #pragma unroll
        for (int i = 0; i < 8; ++i) s += KVp[(size_t)i * (32 * 4160) + idx];
        KVf[idx] = s;
    }
}

// ---------------------------------------------------------------------------
// O1[n, h*64+e] = Z * sum_d q[n,d]*KV[d,e], Z = 1/(q.ksum + 1e-6).
// Q read bf16; O1 emitted single bf16 (gemm2 is 1-term now).
// ---------------------------------------------------------------------------
__global__ __launch_bounds__(256)
void attn_apply_kernel(const ushort* __restrict__ QKV, const float* __restrict__ KVf,
                       ushort* __restrict__ O1)
{
    const int bh = blockIdx.x;
    const int b = bh >> 4, h = bh & 15;
    const int n0 = blockIdx.y * 16;
    const int t = threadIdx.x;
    const int r  = t >> 4;
    const int e0 = (t & 15) * 4;

    __shared__ float kvs[64][68];
    __shared__ float qs[16][68];
    __shared__ float ksums[64];

    const float* kvb = KVf + (size_t)bh * 4160;
    for (int i = t; i < 4096; i += 256)
        kvs[i >> 6][i & 63] = kvb[i];
    if (t < 64) ksums[t] = kvb[4096 + t];
    {
        const int rr = t >> 4, cc2 = (t & 15) * 4;
        short4v q4 = *(const short4v*)&QKV[(size_t)(b * N_SEQ + n0 + rr) * 3072 + h * 64 + cc2];
        qs[rr][cc2 + 0] = bf2f((ushort)q4[0]);
        qs[rr][cc2 + 1] = bf2f((ushort)q4[1]);
        qs[rr][cc2 + 2] = bf2f((ushort)q4[2]);
        qs[rr][cc2 + 3] = bf2f((ushort)q4[3]);
    }
    __syncthreads();

    float4 acc = {0.f, 0.f, 0.f, 0.f};
    float accz = 0.f;
    #pragma unroll
    for (int d = 0; d < 64; ++d) {
        const float qv = qs[r][d];
        const float4 kvv = *(const float4*)&kvs[d][e0];
        acc.x += qv * kvv.x; acc.y += qv * kvv.y;
        acc.z += qv * kvv.z; acc.w += qv * kvv.w;
        accz += qv * ksums[d];
    }
    const float Z = 1.f / (accz + 1e-6f);
    const size_t off = (size_t)(b * N_SEQ + n0 + r) * C_DIM + h * 64 + e0;
    short4v H = {(short)f2bf(acc.x * Z), (short)f2bf(acc.y * Z),
                 (short)f2bf(acc.z * Z), (short)f2bf(acc.w * Z)};
    *(short4v*)&O1[off] = H;
}

extern "C" void kernel_launch(void* const* d_in, const int* in_sizes, int n_in,
                              void* d_out, int out_size, void* d_ws, size_t ws_size,
                              hipStream_t stream)
{
    const float* x   = (const float*)d_in[0];
    const float* Wq  = (const float*)d_in[1];
    const float* Wkv = (const float*)d_in[2];
    const float* Wo  = (const float*)d_in[3];
    const float* bo  = (const float*)d_in[4];
    float* out = (float*)d_out;

    float* ws    = (float*)d_ws;
    ushort* QKVu = (ushort*)ws;                        // 4096*3072 bf16 (24 MB)
    float* KVp   = ws + (size_t)M_ROWS * 3072 / 2;     // 8*32*4160 f32
    float* KVf   = KVp + (size_t)8 * 32 * 4160;        // 32*4160
    ushort* xhi  = (ushort*)(KVf + 32 * 4160);         // 4096*1024 bf16
    ushort* Whi  = xhi + (size_t)M_ROWS * 1024;        // 3072*1024 (Wq;Wkv)
    ushort* Wohi = Whi + (size_t)3072 * 1024;          // 1024*1024
    ushort* O1   = xhi;                                // alias: x dead after GEMM1

    hipFuncSetAttribute((const void*)gemm1_kernel,
                        hipFuncAttributeMaxDynamicSharedMemorySize, 81920);

    // 0. fp32 -> bf16 conversions
    split_all_kernel<<<dim3(4096), 256, 0, stream>>>(
        x, Wq, Wkv, Wo, xhi, Whi, Wohi);

    // 1. fused q/k/v projections, single-term bf16, bf16 output
    gemm1_kernel<<<dim3(512), 256, 81920, stream>>>(xhi, Whi, QKVu);

    // 2-3. KV = K^T V + ksum (8-way split + deterministic reduce)
    kv_partial_kernel<<<dim3(32, 8), 256, 0, stream>>>(QKVu, KVp);
    kv_reduce_kernel<<<dim3((32 * 4160 + 255) / 256), 256, 0, stream>>>(KVp, KVf);

    // 4. O1 = Z * (q @ KV), bf16 out
    attn_apply_kernel<<<dim3(32, 128), 256, 0, stream>>>(QKVu, KVf, O1);

    // 5. final projection + bias (single-term bf16)
    gemm2_kernel<<<dim3(512), 256, 0, stream>>>(O1, Wohi, bo, out);
}